// Round 7
// baseline (694.988 us; speedup 1.0000x reference)
//
#include <hip/hip_runtime.h>
#include <stdint.h>

#define BKT 1024   // nodes per coarse bucket (phase A)
#define SUB 128    // nodes per fine tile   (phase B)
#define EPB 4096   // edges per partition block

// =============== per-node histogram + rowptr ===============

__global__ void hist_kernel(const int* __restrict__ dst, int* __restrict__ cnt, int E) {
    int i = blockIdx.x * blockDim.x + threadIdx.x;
    if (i < E) atomicAdd(&cnt[dst[i]], 1);
}

__global__ void scan_sums(const int* __restrict__ cnt, int* __restrict__ sums, int N) {
    __shared__ int lds[4];
    int base = blockIdx.x * 1024;
    int s = 0;
    for (int i = threadIdx.x; i < 1024; i += 256) {
        int idx = base + i;
        if (idx < N) s += cnt[idx];
    }
    for (int d = 32; d; d >>= 1) s += __shfl_down(s, d);
    int wid = threadIdx.x >> 6;
    if ((threadIdx.x & 63) == 0) lds[wid] = s;
    __syncthreads();
    if (threadIdx.x == 0) sums[blockIdx.x] = lds[0] + lds[1] + lds[2] + lds[3];
}

__global__ void scan_offsets(int* __restrict__ sums, int nb) {
    if (threadIdx.x == 0 && blockIdx.x == 0) {
        int run = 0;
        for (int i = 0; i < nb; ++i) { int v = sums[i]; sums[i] = run; run += v; }
    }
}

__global__ __launch_bounds__(256) void scan_write(const int* __restrict__ cnt,
                                                  const int* __restrict__ sums,
                                                  int* __restrict__ rowptr, int N, int E) {
    __shared__ int lds[256];
    int base = blockIdx.x * 1024;
    int off = sums[blockIdx.x];
    for (int c = 0; c < 4; ++c) {
        int idx = base + c * 256 + threadIdx.x;
        int v = (idx < N) ? cnt[idx] : 0;
        lds[threadIdx.x] = v;
        __syncthreads();
        for (int d = 1; d < 256; d <<= 1) {
            int t = (threadIdx.x >= d) ? lds[threadIdx.x - d] : 0;
            __syncthreads();
            lds[threadIdx.x] += t;
            __syncthreads();
        }
        int incl = lds[threadIdx.x];
        if (idx < N) rowptr[idx] = off + incl - v;
        off += lds[255];
        __syncthreads();
    }
    if (blockIdx.x == 0 && threadIdx.x == 0) rowptr[N] = E;
}

// =============== Phase A: LDS-staged counting-sort partition by dst>>10 ===============

__global__ __launch_bounds__(256) void partition_kernel(const int* __restrict__ src,
                                                        const int* __restrict__ dst,
                                                        const int* __restrict__ rowptr,
                                                        int* __restrict__ gbcur,
                                                        int2* __restrict__ pairs,
                                                        int E, int NBK) {
    __shared__ int2 stage[EPB];          // 32 KB
    __shared__ int  hist[128], offs[129], gbase[128], lcur[128];
    int base = blockIdx.x * EPB;
    int cntE = min(EPB, E - base);
    if (threadIdx.x < 128) hist[threadIdx.x] = 0;
    __syncthreads();
    for (int i = threadIdx.x; i < cntE; i += 256) {
        int b = dst[base + i] >> 10;
        atomicAdd(&hist[b], 1);
    }
    __syncthreads();
    if (threadIdx.x == 0) {
        int run = 0;
        for (int b = 0; b < NBK; ++b) { offs[b] = run; run += hist[b]; }
        offs[NBK] = run;
    }
    __syncthreads();
    if (threadIdx.x < NBK) {
        int b = threadIdx.x;
        int h = hist[b];
        if (h > 0) gbase[b] = rowptr[b << 10] + atomicAdd(&gbcur[b << 4], h);
        lcur[b] = offs[b];
    }
    __syncthreads();
    for (int i = threadIdx.x; i < cntE; i += 256) {
        int e = base + i;
        int d = dst[e];
        int b = d >> 10;
        int slot = atomicAdd(&lcur[b], 1);
        stage[slot] = make_int2(src[e], d);
    }
    __syncthreads();
    int total = offs[NBK];
    for (int j = threadIdx.x; j < total; j += 256) {
        int lo = 0, hi = NBK;
        while (lo < hi) { int mid = (lo + hi) >> 1; if (offs[mid + 1] <= j) lo = mid + 1; else hi = mid; }
        pairs[gbase[lo] + (j - offs[lo])] = stage[j];
    }
}

// =============== Phase B: per-128-node tile scatter ===============

__global__ __launch_bounds__(256) void subscatter_kernel(const int2* __restrict__ pairs,
                                                         const int* __restrict__ rowptr,
                                                         int* __restrict__ csr, int N) {
    __shared__ int curs[SUB];
    int sbase = blockIdx.x * SUB;
    int top = min(sbase + SUB, N);
    if (threadIdx.x < top - sbase) curs[threadIdx.x] = rowptr[sbase + threadIdx.x];
    __syncthreads();
    int parent = sbase >> 10;
    int pbeg = rowptr[parent << 10];
    int pend = rowptr[min((parent + 1) << 10, N)];
    for (int j = pbeg + (int)threadIdx.x; j < pend; j += 256) {
        int2 p = pairs[j];
        unsigned local = (unsigned)(p.y - sbase);
        if (local < SUB) {
            int slot = atomicAdd(&curs[local], 1);
            csr[slot] = p.x;
        }
    }
}

// =============== K1: g1 = (X[N,128] @ W1[128,64]) * dinv ===============

__global__ __launch_bounds__(256) void gemm1_kernel(const float* __restrict__ X,
                                                    const float* __restrict__ W,
                                                    const int* __restrict__ rowptr,
                                                    float* __restrict__ Y, int N) {
    __shared__ float Ws[128 * 64];   // 32 KB
    __shared__ float Xs[16][132];
    {
        const float4* Wv = (const float4*)W;
        float4* Wsv = (float4*)Ws;
        for (int i = threadIdx.x; i < 128 * 16; i += 256) Wsv[i] = Wv[i];
    }
    int row = threadIdx.x >> 4;
    int node0 = blockIdx.x * 16;
    int node = node0 + row;
    {
        const float4* Xv = (const float4*)(X + (size_t)node0 * 128);
        for (int i = threadIdx.x; i < 512; i += 256) {
            int r = i >> 5, kk = i & 31;
            if (node0 + r < N) *(float4*)&Xs[r][kk * 4] = Xv[(size_t)r * 32 + kk];
        }
    }
    __syncthreads();
    if (node >= N) return;
    int c = (threadIdx.x & 15) * 4;
    float4 acc = make_float4(0.f, 0.f, 0.f, 0.f);
#pragma unroll 16
    for (int k = 0; k < 128; ++k) {
        float xv = Xs[row][k];
        float4 wv = *(const float4*)&Ws[k * 64 + c];
        acc.x += xv * wv.x; acc.y += xv * wv.y;
        acc.z += xv * wv.z; acc.w += xv * wv.w;
    }
    float w = rsqrtf((float)(rowptr[node + 1] - rowptr[node]) + 1.0f);
    acc.x *= w; acc.y *= w; acc.z *= w; acc.w *= w;
    *(float4*)&Y[(size_t)node * 64 + c] = acc;
}

// =============== fused: h = relu(dinv*agg(g) + b); out = (h @ W) * dinv ===============
// 8-deep gather pipeline; GEMM h-broadcast via 16-lane shuffles (no T tile).

__global__ __launch_bounds__(256, 6) void fused_layer_kernel(const float* __restrict__ g,
                                                             const int* __restrict__ rowptr,
                                                             const int* __restrict__ csr,
                                                             const float* __restrict__ bias,
                                                             const float* __restrict__ W,
                                                             float* __restrict__ out, int N) {
    __shared__ float Ws[64 * 64];    // 16 KB
    {
        const float4* Wv = (const float4*)W;
        float4* Wsv = (float4*)Ws;
        for (int i = threadIdx.x; i < 64 * 16; i += 256) Wsv[i] = Wv[i];
    }
    int row = threadIdx.x >> 4;
    int node = blockIdx.x * 16 + row;
    bool valid = node < N;
    int nc = valid ? node : N - 1;
    int t = threadIdx.x & 15;
    const float4* g4 = (const float4*)g;

    int beg = rowptr[nc], end = rowptr[nc + 1];
    float dinv = rsqrtf((float)(end - beg) + 1.0f);
    float4 acc = g4[(size_t)nc * 16 + t];      // self-loop
    int j = beg;
    for (; j + 8 <= end; j += 8) {
        int s0 = csr[j], s1 = csr[j + 1], s2 = csr[j + 2], s3 = csr[j + 3];
        int s4 = csr[j + 4], s5 = csr[j + 5], s6 = csr[j + 6], s7 = csr[j + 7];
        float4 v0 = g4[(size_t)s0 * 16 + t];
        float4 v1 = g4[(size_t)s1 * 16 + t];
        float4 v2 = g4[(size_t)s2 * 16 + t];
        float4 v3 = g4[(size_t)s3 * 16 + t];
        float4 v4 = g4[(size_t)s4 * 16 + t];
        float4 v5 = g4[(size_t)s5 * 16 + t];
        float4 v6 = g4[(size_t)s6 * 16 + t];
        float4 v7 = g4[(size_t)s7 * 16 + t];
        acc.x += ((v0.x + v1.x) + (v2.x + v3.x)) + ((v4.x + v5.x) + (v6.x + v7.x));
        acc.y += ((v0.y + v1.y) + (v2.y + v3.y)) + ((v4.y + v5.y) + (v6.y + v7.y));
        acc.z += ((v0.z + v1.z) + (v2.z + v3.z)) + ((v4.z + v5.z) + (v6.z + v7.z));
        acc.w += ((v0.w + v1.w) + (v2.w + v3.w)) + ((v4.w + v5.w) + (v6.w + v7.w));
    }
    for (; j + 2 <= end; j += 2) {
        int s0 = csr[j], s1 = csr[j + 1];
        float4 v0 = g4[(size_t)s0 * 16 + t];
        float4 v1 = g4[(size_t)s1 * 16 + t];
        acc.x += v0.x + v1.x; acc.y += v0.y + v1.y;
        acc.z += v0.z + v1.z; acc.w += v0.w + v1.w;
    }
    if (j < end) {
        int s0 = csr[j];
        float4 v0 = g4[(size_t)s0 * 16 + t];
        acc.x += v0.x; acc.y += v0.y; acc.z += v0.z; acc.w += v0.w;
    }
    float4 bb = *(const float4*)&bias[t * 4];
    float hx = fmaxf(acc.x * dinv + bb.x, 0.f);
    float hy = fmaxf(acc.y * dinv + bb.y, 0.f);
    float hz = fmaxf(acc.z * dinv + bb.z, 0.f);
    float hw = fmaxf(acc.w * dinv + bb.w, 0.f);

    __syncthreads();   // Ws staging complete (overlapped with gathers)

    float4 o = make_float4(0.f, 0.f, 0.f, 0.f);
    int gb = threadIdx.x & 48;         // group base lane within wave
    int c = t * 4;
#pragma unroll
    for (int kl = 0; kl < 16; ++kl) {
        int sl = gb + kl;
        float h0 = __shfl(hx, sl, 64);
        float h1 = __shfl(hy, sl, 64);
        float h2 = __shfl(hz, sl, 64);
        float h3 = __shfl(hw, sl, 64);
        float4 w0 = *(const float4*)&Ws[(kl * 4 + 0) * 64 + c];
        float4 w1 = *(const float4*)&Ws[(kl * 4 + 1) * 64 + c];
        float4 w2 = *(const float4*)&Ws[(kl * 4 + 2) * 64 + c];
        float4 w3 = *(const float4*)&Ws[(kl * 4 + 3) * 64 + c];
        o.x += h0 * w0.x + h1 * w1.x + h2 * w2.x + h3 * w3.x;
        o.y += h0 * w0.y + h1 * w1.y + h2 * w2.y + h3 * w3.y;
        o.z += h0 * w0.z + h1 * w1.z + h2 * w2.z + h3 * w3.z;
        o.w += h0 * w0.w + h1 * w1.w + h2 * w2.w + h3 * w3.w;
    }
    o.x *= dinv; o.y *= dinv; o.z *= dinv; o.w *= dinv;
    if (valid) *(float4*)&out[(size_t)node * 64 + c] = o;
}

// =============== K4: h3 = dinv*agg(g3) + b3;  s_node = h3 . Wl ===============

__global__ __launch_bounds__(256, 6) void agg_dot_kernel(const float* __restrict__ g,
                                                         const int* __restrict__ rowptr,
                                                         const int* __restrict__ csr,
                                                         const float* __restrict__ bias,
                                                         const float* __restrict__ Wl,
                                                         float* __restrict__ s_node, int N) {
    int tid = blockIdx.x * blockDim.x + threadIdx.x;
    int node = tid >> 4;
    if (node >= N) return;
    int t = tid & 15;
    const float4* g4 = (const float4*)g;
    int beg = rowptr[node], end = rowptr[node + 1];
    float dinv = rsqrtf((float)(end - beg) + 1.0f);
    float4 acc = g4[(size_t)node * 16 + t];
    int j = beg;
    for (; j + 8 <= end; j += 8) {
        int s0 = csr[j], s1 = csr[j + 1], s2 = csr[j + 2], s3 = csr[j + 3];
        int s4 = csr[j + 4], s5 = csr[j + 5], s6 = csr[j + 6], s7 = csr[j + 7];
        float4 v0 = g4[(size_t)s0 * 16 + t];
        float4 v1 = g4[(size_t)s1 * 16 + t];
        float4 v2 = g4[(size_t)s2 * 16 + t];
        float4 v3 = g4[(size_t)s3 * 16 + t];
        float4 v4 = g4[(size_t)s4 * 16 + t];
        float4 v5 = g4[(size_t)s5 * 16 + t];
        float4 v6 = g4[(size_t)s6 * 16 + t];
        float4 v7 = g4[(size_t)s7 * 16 + t];
        acc.x += ((v0.x + v1.x) + (v2.x + v3.x)) + ((v4.x + v5.x) + (v6.x + v7.x));
        acc.y += ((v0.y + v1.y) + (v2.y + v3.y)) + ((v4.y + v5.y) + (v6.y + v7.y));
        acc.z += ((v0.z + v1.z) + (v2.z + v3.z)) + ((v4.z + v5.z) + (v6.z + v7.z));
        acc.w += ((v0.w + v1.w) + (v2.w + v3.w)) + ((v4.w + v5.w) + (v6.w + v7.w));
    }
    for (; j + 2 <= end; j += 2) {
        int s0 = csr[j], s1 = csr[j + 1];
        float4 v0 = g4[(size_t)s0 * 16 + t];
        float4 v1 = g4[(size_t)s1 * 16 + t];
        acc.x += v0.x + v1.x; acc.y += v0.y + v1.y;
        acc.z += v0.z + v1.z; acc.w += v0.w + v1.w;
    }
    if (j < end) {
        int s0 = csr[j];
        float4 v0 = g4[(size_t)s0 * 16 + t];
        acc.x += v0.x; acc.y += v0.y; acc.z += v0.z; acc.w += v0.w;
    }
    float4 bb = *(const float4*)&bias[t * 4];
    float4 wl = *(const float4*)&Wl[t * 4];
    float s = (acc.x * dinv + bb.x) * wl.x + (acc.y * dinv + bb.y) * wl.y +
              (acc.z * dinv + bb.z) * wl.z + (acc.w * dinv + bb.w) * wl.w;
    s += __shfl_xor(s, 1);
    s += __shfl_xor(s, 2);
    s += __shfl_xor(s, 4);
    s += __shfl_xor(s, 8);
    if (t == 0) s_node[node] = s;
}

// =============== K5: per-graph mean over sorted batch + bl ===============

__device__ __forceinline__ int lower_bound_dev(const int* __restrict__ a, int n, int v) {
    int lo = 0, hi = n;
    while (lo < hi) { int mid = (lo + hi) >> 1; if (a[mid] < v) lo = mid + 1; else hi = mid; }
    return lo;
}

__global__ void pool_out_kernel(const float* __restrict__ s_node, const int* __restrict__ batch,
                                const float* __restrict__ bl, float* __restrict__ out, int N) {
    int gidx = blockIdx.x;
    int lo = lower_bound_dev(batch, N, gidx);
    int hi = lower_bound_dev(batch, N, gidx + 1);
    float s = 0.f;
    for (int i = lo + threadIdx.x; i < hi; i += 64) s += s_node[i];
    for (int d = 32; d; d >>= 1) s += __shfl_down(s, d);
    if (threadIdx.x == 0) out[gidx] = s / fmaxf((float)(hi - lo), 1.0f) + bl[0];
}

// =============== launcher ===============

extern "C" void kernel_launch(void* const* d_in, const int* in_sizes, int n_in,
                              void* d_out, int out_size, void* d_ws, size_t ws_size,
                              hipStream_t stream) {
    const float* x   = (const float*)d_in[0];
    const int*   ei  = (const int*)d_in[1];
    const int*   bat = (const int*)d_in[2];
    const float* W1  = (const float*)d_in[3];
    const float* b1  = (const float*)d_in[4];
    const float* W2  = (const float*)d_in[5];
    const float* b2  = (const float*)d_in[6];
    const float* W3  = (const float*)d_in[7];
    const float* b3  = (const float*)d_in[8];
    const float* Wl  = (const float*)d_in[9];
    const float* bl  = (const float*)d_in[10];

    const int N = in_sizes[0] / 128;   // 100000
    const int E = in_sizes[1] / 2;     // 1600000
    const int G = out_size;            // 1000

    const int* src = ei;
    const int* dst = ei + E;

    const int NBK  = (N + BKT - 1) / BKT;      // coarse buckets (98)
    const int NSUB = (N + SUB - 1) / SUB;      // fine tiles (782)
    const int Np = (N + 4) & ~3;

    // workspace layout
    int*   cnt    = (int*)d_ws;                // N   : hist -> (later) s_node
    int*   rowptr = cnt + N;                   // Np
    int*   sums   = rowptr + Np;               // 1024
    int*   gbcur  = sums + 1024;               // NBK*16 padded cursors
    int*   csr    = gbcur + (size_t)NBK * 16;  // E
    float* bufA   = (float*)(csr + E);         // N*64
    float* bufB   = bufA + (size_t)N * 64;     // N*64
    float* s_node = (float*)cnt;
    int2*  pairs  = (int2*)bufA;               // aliases bufA (dead until gemm1)

    const int nb = (N + 1023) / 1024;

    // ---- rowptr ----
    hipMemsetAsync(cnt, 0, (size_t)N * sizeof(int), stream);
    hipMemsetAsync(gbcur, 0, (size_t)NBK * 16 * sizeof(int), stream);
    hist_kernel<<<(E + 255) / 256, 256, 0, stream>>>(dst, cnt, E);
    scan_sums<<<nb, 256, 0, stream>>>(cnt, sums, N);
    scan_offsets<<<1, 64, 0, stream>>>(sums, nb);
    scan_write<<<nb, 256, 0, stream>>>(cnt, sums, rowptr, N, E);

    // ---- two-phase CSR fill ----
    partition_kernel<<<(E + EPB - 1) / EPB, 256, 0, stream>>>(src, dst, rowptr, gbcur, pairs, E, NBK);
    subscatter_kernel<<<NSUB, 256, 0, stream>>>(pairs, rowptr, csr, N);

    const int tileGrid = (N + 15) / 16;
    const int aggGrid  = (int)(((size_t)N * 16 + 255) / 256);

    gemm1_kernel<<<tileGrid, 256, 0, stream>>>(x, W1, rowptr, bufA, N);
    fused_layer_kernel<<<tileGrid, 256, 0, stream>>>(bufA, rowptr, csr, b1, W2, bufB, N);
    fused_layer_kernel<<<tileGrid, 256, 0, stream>>>(bufB, rowptr, csr, b2, W3, bufA, N);
    agg_dot_kernel<<<aggGrid, 256, 0, stream>>>(bufA, rowptr, csr, b3, Wl, s_node, N);
    pool_out_kernel<<<G, 64, 0, stream>>>(s_node, bat, bl, (float*)d_out, N);
}

// Round 8
// 453.484 us; speedup vs baseline: 1.5326x; 1.5326x over previous
//
#include <hip/hip_runtime.h>
#include <stdint.h>

#define BKT 1024   // nodes per coarse bucket (phase A)
#define SUB 128    // nodes per fine tile   (phase B)
#define EPB 4096   // edges per partition block

// =============== per-node histogram + rowptr ===============

__global__ void hist_kernel(const int* __restrict__ dst, int* __restrict__ cnt, int E) {
    int i = blockIdx.x * blockDim.x + threadIdx.x;
    if (i < E) atomicAdd(&cnt[dst[i]], 1);
}

__global__ void scan_sums(const int* __restrict__ cnt, int* __restrict__ sums, int N) {
    __shared__ int lds[4];
    int base = blockIdx.x * 1024;
    int s = 0;
    for (int i = threadIdx.x; i < 1024; i += 256) {
        int idx = base + i;
        if (idx < N) s += cnt[idx];
    }
    for (int d = 32; d; d >>= 1) s += __shfl_down(s, d);
    int wid = threadIdx.x >> 6;
    if ((threadIdx.x & 63) == 0) lds[wid] = s;
    __syncthreads();
    if (threadIdx.x == 0) sums[blockIdx.x] = lds[0] + lds[1] + lds[2] + lds[3];
}

__global__ void scan_offsets(int* __restrict__ sums, int nb) {
    if (threadIdx.x == 0 && blockIdx.x == 0) {
        int run = 0;
        for (int i = 0; i < nb; ++i) { int v = sums[i]; sums[i] = run; run += v; }
    }
}

__global__ __launch_bounds__(256) void scan_write(const int* __restrict__ cnt,
                                                  const int* __restrict__ sums,
                                                  int* __restrict__ rowptr, int N, int E) {
    __shared__ int lds[256];
    int base = blockIdx.x * 1024;
    int off = sums[blockIdx.x];
    for (int c = 0; c < 4; ++c) {
        int idx = base + c * 256 + threadIdx.x;
        int v = (idx < N) ? cnt[idx] : 0;
        lds[threadIdx.x] = v;
        __syncthreads();
        for (int d = 1; d < 256; d <<= 1) {
            int t = (threadIdx.x >= d) ? lds[threadIdx.x - d] : 0;
            __syncthreads();
            lds[threadIdx.x] += t;
            __syncthreads();
        }
        int incl = lds[threadIdx.x];
        if (idx < N) rowptr[idx] = off + incl - v;
        off += lds[255];
        __syncthreads();
    }
    if (blockIdx.x == 0 && threadIdx.x == 0) rowptr[N] = E;
}

// =============== Phase A: LDS-staged counting-sort partition by dst>>10 ===============

__global__ __launch_bounds__(256) void partition_kernel(const int* __restrict__ src,
                                                        const int* __restrict__ dst,
                                                        const int* __restrict__ rowptr,
                                                        int* __restrict__ gbcur,
                                                        int2* __restrict__ pairs,
                                                        int E, int NBK) {
    __shared__ int2 stage[EPB];          // 32 KB
    __shared__ int  hist[128], offs[129], gbase[128], lcur[128];
    int base = blockIdx.x * EPB;
    int cntE = min(EPB, E - base);
    if (threadIdx.x < 128) hist[threadIdx.x] = 0;
    __syncthreads();
    for (int i = threadIdx.x; i < cntE; i += 256) {
        int b = dst[base + i] >> 10;
        atomicAdd(&hist[b], 1);
    }
    __syncthreads();
    if (threadIdx.x == 0) {
        int run = 0;
        for (int b = 0; b < NBK; ++b) { offs[b] = run; run += hist[b]; }
        offs[NBK] = run;
    }
    __syncthreads();
    if (threadIdx.x < NBK) {
        int b = threadIdx.x;
        int h = hist[b];
        if (h > 0) gbase[b] = rowptr[b << 10] + atomicAdd(&gbcur[b << 4], h);
        lcur[b] = offs[b];
    }
    __syncthreads();
    for (int i = threadIdx.x; i < cntE; i += 256) {
        int e = base + i;
        int d = dst[e];
        int b = d >> 10;
        int slot = atomicAdd(&lcur[b], 1);
        stage[slot] = make_int2(src[e], d);
    }
    __syncthreads();
    int total = offs[NBK];
    for (int j = threadIdx.x; j < total; j += 256) {
        int lo = 0, hi = NBK;
        while (lo < hi) { int mid = (lo + hi) >> 1; if (offs[mid + 1] <= j) lo = mid + 1; else hi = mid; }
        pairs[gbase[lo] + (j - offs[lo])] = stage[j];
    }
}

// =============== Phase B: per-128-node tile scatter ===============

__global__ __launch_bounds__(256) void subscatter_kernel(const int2* __restrict__ pairs,
                                                         const int* __restrict__ rowptr,
                                                         int* __restrict__ csr, int N) {
    __shared__ int curs[SUB];
    int sbase = blockIdx.x * SUB;
    int top = min(sbase + SUB, N);
    if (threadIdx.x < top - sbase) curs[threadIdx.x] = rowptr[sbase + threadIdx.x];
    __syncthreads();
    int parent = sbase >> 10;
    int pbeg = rowptr[parent << 10];
    int pend = rowptr[min((parent + 1) << 10, N)];
    for (int j = pbeg + (int)threadIdx.x; j < pend; j += 256) {
        int2 p = pairs[j];
        unsigned local = (unsigned)(p.y - sbase);
        if (local < SUB) {
            int slot = atomicAdd(&curs[local], 1);
            csr[slot] = p.x;
        }
    }
}

// =============== K1: g1 = (X[N,128] @ W1[128,64]) * dinv ===============

__global__ __launch_bounds__(256) void gemm1_kernel(const float* __restrict__ X,
                                                    const float* __restrict__ W,
                                                    const int* __restrict__ rowptr,
                                                    float* __restrict__ Y, int N) {
    __shared__ float Ws[128 * 64];   // 32 KB
    __shared__ float Xs[16][132];
    {
        const float4* Wv = (const float4*)W;
        float4* Wsv = (float4*)Ws;
        for (int i = threadIdx.x; i < 128 * 16; i += 256) Wsv[i] = Wv[i];
    }
    int row = threadIdx.x >> 4;
    int node0 = blockIdx.x * 16;
    int node = node0 + row;
    {
        const float4* Xv = (const float4*)(X + (size_t)node0 * 128);
        for (int i = threadIdx.x; i < 512; i += 256) {
            int r = i >> 5, kk = i & 31;
            if (node0 + r < N) *(float4*)&Xs[r][kk * 4] = Xv[(size_t)r * 32 + kk];
        }
    }
    __syncthreads();
    if (node >= N) return;
    int c = (threadIdx.x & 15) * 4;
    float4 acc = make_float4(0.f, 0.f, 0.f, 0.f);
#pragma unroll 16
    for (int k = 0; k < 128; ++k) {
        float xv = Xs[row][k];
        float4 wv = *(const float4*)&Ws[k * 64 + c];
        acc.x += xv * wv.x; acc.y += xv * wv.y;
        acc.z += xv * wv.z; acc.w += xv * wv.w;
    }
    float w = rsqrtf((float)(rowptr[node + 1] - rowptr[node]) + 1.0f);
    acc.x *= w; acc.y *= w; acc.z *= w; acc.w *= w;
    *(float4*)&Y[(size_t)node * 64 + c] = acc;
}

// =============== fused: h = relu(dinv*agg(g) + b); out = (h @ W) * dinv ===============
// Round-6 structure (T tile), 8-deep gather unroll, NO register-capping bound.

__global__ __launch_bounds__(256) void fused_layer_kernel(const float* __restrict__ g,
                                                          const int* __restrict__ rowptr,
                                                          const int* __restrict__ csr,
                                                          const float* __restrict__ bias,
                                                          const float* __restrict__ W,
                                                          float* __restrict__ out, int N) {
    __shared__ float Ws[64 * 64];    // 16 KB
    __shared__ float T[16][72];
    {
        const float4* Wv = (const float4*)W;
        float4* Wsv = (float4*)Ws;
        for (int i = threadIdx.x; i < 64 * 16; i += 256) Wsv[i] = Wv[i];
    }
    int row = threadIdx.x >> 4;
    int node = blockIdx.x * 16 + row;
    int t = threadIdx.x & 15;
    int c = t * 4;
    float dinv = 0.f;
    const float4* g4 = (const float4*)g;
    if (node < N) {
        int beg = rowptr[node], end = rowptr[node + 1];
        dinv = rsqrtf((float)(end - beg) + 1.0f);
        float4 acc = g4[(size_t)node * 16 + t];   // self-loop
        int j = beg;
        for (; j + 8 <= end; j += 8) {
            int s0 = csr[j], s1 = csr[j + 1], s2 = csr[j + 2], s3 = csr[j + 3];
            int s4 = csr[j + 4], s5 = csr[j + 5], s6 = csr[j + 6], s7 = csr[j + 7];
            float4 v0 = g4[(size_t)s0 * 16 + t];
            float4 v1 = g4[(size_t)s1 * 16 + t];
            float4 v2 = g4[(size_t)s2 * 16 + t];
            float4 v3 = g4[(size_t)s3 * 16 + t];
            float4 v4 = g4[(size_t)s4 * 16 + t];
            float4 v5 = g4[(size_t)s5 * 16 + t];
            float4 v6 = g4[(size_t)s6 * 16 + t];
            float4 v7 = g4[(size_t)s7 * 16 + t];
            acc.x += ((v0.x + v1.x) + (v2.x + v3.x)) + ((v4.x + v5.x) + (v6.x + v7.x));
            acc.y += ((v0.y + v1.y) + (v2.y + v3.y)) + ((v4.y + v5.y) + (v6.y + v7.y));
            acc.z += ((v0.z + v1.z) + (v2.z + v3.z)) + ((v4.z + v5.z) + (v6.z + v7.z));
            acc.w += ((v0.w + v1.w) + (v2.w + v3.w)) + ((v4.w + v5.w) + (v6.w + v7.w));
        }
        for (; j + 2 <= end; j += 2) {
            int s0 = csr[j], s1 = csr[j + 1];
            float4 v0 = g4[(size_t)s0 * 16 + t];
            float4 v1 = g4[(size_t)s1 * 16 + t];
            acc.x += v0.x + v1.x; acc.y += v0.y + v1.y;
            acc.z += v0.z + v1.z; acc.w += v0.w + v1.w;
        }
        if (j < end) {
            int s0 = csr[j];
            float4 v0 = g4[(size_t)s0 * 16 + t];
            acc.x += v0.x; acc.y += v0.y; acc.z += v0.z; acc.w += v0.w;
        }
        float4 bb = *(const float4*)&bias[c];
        T[row][c + 0] = fmaxf(acc.x * dinv + bb.x, 0.f);
        T[row][c + 1] = fmaxf(acc.y * dinv + bb.y, 0.f);
        T[row][c + 2] = fmaxf(acc.z * dinv + bb.z, 0.f);
        T[row][c + 3] = fmaxf(acc.w * dinv + bb.w, 0.f);
    }
    __syncthreads();
    if (node >= N) return;
    float4 o = make_float4(0.f, 0.f, 0.f, 0.f);
#pragma unroll 16
    for (int k = 0; k < 64; ++k) {
        float tv = T[row][k];
        float4 wv = *(const float4*)&Ws[k * 64 + c];
        o.x += tv * wv.x; o.y += tv * wv.y;
        o.z += tv * wv.z; o.w += tv * wv.w;
    }
    o.x *= dinv; o.y *= dinv; o.z *= dinv; o.w *= dinv;
    *(float4*)&out[(size_t)node * 64 + c] = o;
}

// =============== K4: h3 = dinv*agg(g3) + b3;  s_node = h3 . Wl ===============

__global__ __launch_bounds__(256) void agg_dot_kernel(const float* __restrict__ g,
                                                      const int* __restrict__ rowptr,
                                                      const int* __restrict__ csr,
                                                      const float* __restrict__ bias,
                                                      const float* __restrict__ Wl,
                                                      float* __restrict__ s_node, int N) {
    int tid = blockIdx.x * blockDim.x + threadIdx.x;
    int node = tid >> 4;
    if (node >= N) return;
    int t = tid & 15;
    const float4* g4 = (const float4*)g;
    int beg = rowptr[node], end = rowptr[node + 1];
    float dinv = rsqrtf((float)(end - beg) + 1.0f);
    float4 acc = g4[(size_t)node * 16 + t];
    int j = beg;
    for (; j + 8 <= end; j += 8) {
        int s0 = csr[j], s1 = csr[j + 1], s2 = csr[j + 2], s3 = csr[j + 3];
        int s4 = csr[j + 4], s5 = csr[j + 5], s6 = csr[j + 6], s7 = csr[j + 7];
        float4 v0 = g4[(size_t)s0 * 16 + t];
        float4 v1 = g4[(size_t)s1 * 16 + t];
        float4 v2 = g4[(size_t)s2 * 16 + t];
        float4 v3 = g4[(size_t)s3 * 16 + t];
        float4 v4 = g4[(size_t)s4 * 16 + t];
        float4 v5 = g4[(size_t)s5 * 16 + t];
        float4 v6 = g4[(size_t)s6 * 16 + t];
        float4 v7 = g4[(size_t)s7 * 16 + t];
        acc.x += ((v0.x + v1.x) + (v2.x + v3.x)) + ((v4.x + v5.x) + (v6.x + v7.x));
        acc.y += ((v0.y + v1.y) + (v2.y + v3.y)) + ((v4.y + v5.y) + (v6.y + v7.y));
        acc.z += ((v0.z + v1.z) + (v2.z + v3.z)) + ((v4.z + v5.z) + (v6.z + v7.z));
        acc.w += ((v0.w + v1.w) + (v2.w + v3.w)) + ((v4.w + v5.w) + (v6.w + v7.w));
    }
    for (; j + 2 <= end; j += 2) {
        int s0 = csr[j], s1 = csr[j + 1];
        float4 v0 = g4[(size_t)s0 * 16 + t];
        float4 v1 = g4[(size_t)s1 * 16 + t];
        acc.x += v0.x + v1.x; acc.y += v0.y + v1.y;
        acc.z += v0.z + v1.z; acc.w += v0.w + v1.w;
    }
    if (j < end) {
        int s0 = csr[j];
        float4 v0 = g4[(size_t)s0 * 16 + t];
        acc.x += v0.x; acc.y += v0.y; acc.z += v0.z; acc.w += v0.w;
    }
    float4 bb = *(const float4*)&bias[t * 4];
    float4 wl = *(const float4*)&Wl[t * 4];
    float s = (acc.x * dinv + bb.x) * wl.x + (acc.y * dinv + bb.y) * wl.y +
              (acc.z * dinv + bb.z) * wl.z + (acc.w * dinv + bb.w) * wl.w;
    s += __shfl_xor(s, 1);
    s += __shfl_xor(s, 2);
    s += __shfl_xor(s, 4);
    s += __shfl_xor(s, 8);
    if (t == 0) s_node[node] = s;
}

// =============== K5: per-graph mean over sorted batch + bl ===============

__device__ __forceinline__ int lower_bound_dev(const int* __restrict__ a, int n, int v) {
    int lo = 0, hi = n;
    while (lo < hi) { int mid = (lo + hi) >> 1; if (a[mid] < v) lo = mid + 1; else hi = mid; }
    return lo;
}

__global__ void pool_out_kernel(const float* __restrict__ s_node, const int* __restrict__ batch,
                                const float* __restrict__ bl, float* __restrict__ out, int N) {
    int gidx = blockIdx.x;
    int lo = lower_bound_dev(batch, N, gidx);
    int hi = lower_bound_dev(batch, N, gidx + 1);
    float s = 0.f;
    for (int i = lo + threadIdx.x; i < hi; i += 64) s += s_node[i];
    for (int d = 32; d; d >>= 1) s += __shfl_down(s, d);
    if (threadIdx.x == 0) out[gidx] = s / fmaxf((float)(hi - lo), 1.0f) + bl[0];
}

// =============== launcher ===============

extern "C" void kernel_launch(void* const* d_in, const int* in_sizes, int n_in,
                              void* d_out, int out_size, void* d_ws, size_t ws_size,
                              hipStream_t stream) {
    const float* x   = (const float*)d_in[0];
    const int*   ei  = (const int*)d_in[1];
    const int*   bat = (const int*)d_in[2];
    const float* W1  = (const float*)d_in[3];
    const float* b1  = (const float*)d_in[4];
    const float* W2  = (const float*)d_in[5];
    const float* b2  = (const float*)d_in[6];
    const float* W3  = (const float*)d_in[7];
    const float* b3  = (const float*)d_in[8];
    const float* Wl  = (const float*)d_in[9];
    const float* bl  = (const float*)d_in[10];

    const int N = in_sizes[0] / 128;   // 100000
    const int E = in_sizes[1] / 2;     // 1600000
    const int G = out_size;            // 1000

    const int* src = ei;
    const int* dst = ei + E;

    const int NBK  = (N + BKT - 1) / BKT;      // coarse buckets (98)
    const int NSUB = (N + SUB - 1) / SUB;      // fine tiles (782)
    const int Np = (N + 4) & ~3;

    // workspace layout
    int*   cnt    = (int*)d_ws;                // N   : hist -> (later) s_node
    int*   rowptr = cnt + N;                   // Np
    int*   sums   = rowptr + Np;               // 1024
    int*   gbcur  = sums + 1024;               // NBK*16 padded cursors
    int*   csr    = gbcur + (size_t)NBK * 16;  // E
    float* bufA   = (float*)(csr + E);         // N*64
    float* bufB   = bufA + (size_t)N * 64;     // N*64
    float* s_node = (float*)cnt;
    int2*  pairs  = (int2*)bufA;               // aliases bufA (dead until gemm1)

    const int nb = (N + 1023) / 1024;

    // ---- rowptr ----
    hipMemsetAsync(cnt, 0, (size_t)N * sizeof(int), stream);
    hipMemsetAsync(gbcur, 0, (size_t)NBK * 16 * sizeof(int), stream);
    hist_kernel<<<(E + 255) / 256, 256, 0, stream>>>(dst, cnt, E);
    scan_sums<<<nb, 256, 0, stream>>>(cnt, sums, N);
    scan_offsets<<<1, 64, 0, stream>>>(sums, nb);
    scan_write<<<nb, 256, 0, stream>>>(cnt, sums, rowptr, N, E);

    // ---- two-phase CSR fill ----
    partition_kernel<<<(E + EPB - 1) / EPB, 256, 0, stream>>>(src, dst, rowptr, gbcur, pairs, E, NBK);
    subscatter_kernel<<<NSUB, 256, 0, stream>>>(pairs, rowptr, csr, N);

    const int tileGrid = (N + 15) / 16;
    const int aggGrid  = (int)(((size_t)N * 16 + 255) / 256);

    gemm1_kernel<<<tileGrid, 256, 0, stream>>>(x, W1, rowptr, bufA, N);
    fused_layer_kernel<<<tileGrid, 256, 0, stream>>>(bufA, rowptr, csr, b1, W2, bufB, N);
    fused_layer_kernel<<<tileGrid, 256, 0, stream>>>(bufB, rowptr, csr, b2, W3, bufA, N);
    agg_dot_kernel<<<aggGrid, 256, 0, stream>>>(bufA, rowptr, csr, b3, Wl, s_node, N);
    pool_out_kernel<<<G, 64, 0, stream>>>(s_node, bat, bl, (float*)d_out, N);
}

// Round 9
// 373.744 us; speedup vs baseline: 1.8595x; 1.2134x over previous
//
#include <hip/hip_runtime.h>
#include <stdint.h>

#define BKT 1024   // nodes per coarse bucket (phase A)
#define SUB 128    // nodes per fine tile   (phase B)
#define EPB 4096   // edges per partition block

// ---- bf16 helpers (RNE pack, exact expand) ----
__device__ __forceinline__ unsigned short f2bf(float f) {
    unsigned u = __float_as_uint(f);
    u = u + 0x7FFFu + ((u >> 16) & 1u);
    return (unsigned short)(u >> 16);
}
__device__ __forceinline__ float bf2f(unsigned short h) {
    return __uint_as_float(((unsigned)h) << 16);
}
__device__ __forceinline__ float4 bf4(ushort4 v) {
    return make_float4(bf2f(v.x), bf2f(v.y), bf2f(v.z), bf2f(v.w));
}
__device__ __forceinline__ ushort4 pack4(float a, float b, float c, float d) {
    ushort4 r; r.x = f2bf(a); r.y = f2bf(b); r.z = f2bf(c); r.w = f2bf(d); return r;
}

// =============== per-node histogram + rowptr ===============

__global__ void hist_kernel(const int* __restrict__ dst, int* __restrict__ cnt, int E) {
    int i = blockIdx.x * blockDim.x + threadIdx.x;
    if (i < E) atomicAdd(&cnt[dst[i]], 1);
}

__global__ void scan_sums(const int* __restrict__ cnt, int* __restrict__ sums, int N) {
    __shared__ int lds[4];
    int base = blockIdx.x * 1024;
    int s = 0;
    for (int i = threadIdx.x; i < 1024; i += 256) {
        int idx = base + i;
        if (idx < N) s += cnt[idx];
    }
    for (int d = 32; d; d >>= 1) s += __shfl_down(s, d);
    int wid = threadIdx.x >> 6;
    if ((threadIdx.x & 63) == 0) lds[wid] = s;
    __syncthreads();
    if (threadIdx.x == 0) sums[blockIdx.x] = lds[0] + lds[1] + lds[2] + lds[3];
}

__global__ void scan_offsets(int* __restrict__ sums, int nb) {
    if (threadIdx.x == 0 && blockIdx.x == 0) {
        int run = 0;
        for (int i = 0; i < nb; ++i) { int v = sums[i]; sums[i] = run; run += v; }
    }
}

__global__ __launch_bounds__(256) void scan_write(const int* __restrict__ cnt,
                                                  const int* __restrict__ sums,
                                                  int* __restrict__ rowptr, int N, int E) {
    __shared__ int lds[256];
    int base = blockIdx.x * 1024;
    int off = sums[blockIdx.x];
    for (int c = 0; c < 4; ++c) {
        int idx = base + c * 256 + threadIdx.x;
        int v = (idx < N) ? cnt[idx] : 0;
        lds[threadIdx.x] = v;
        __syncthreads();
        for (int d = 1; d < 256; d <<= 1) {
            int t = (threadIdx.x >= d) ? lds[threadIdx.x - d] : 0;
            __syncthreads();
            lds[threadIdx.x] += t;
            __syncthreads();
        }
        int incl = lds[threadIdx.x];
        if (idx < N) rowptr[idx] = off + incl - v;
        off += lds[255];
        __syncthreads();
    }
    if (blockIdx.x == 0 && threadIdx.x == 0) rowptr[N] = E;
}

// =============== Phase A: LDS-staged counting-sort partition by dst>>10 ===============

__global__ __launch_bounds__(256) void partition_kernel(const int* __restrict__ src,
                                                        const int* __restrict__ dst,
                                                        const int* __restrict__ rowptr,
                                                        int* __restrict__ gbcur,
                                                        int2* __restrict__ pairs,
                                                        int E, int NBK) {
    __shared__ int2 stage[EPB];          // 32 KB
    __shared__ int  hist[128], offs[129], gbase[128], lcur[128];
    int base = blockIdx.x * EPB;
    int cntE = min(EPB, E - base);
    if (threadIdx.x < 128) hist[threadIdx.x] = 0;
    __syncthreads();
    for (int i = threadIdx.x; i < cntE; i += 256) {
        int b = dst[base + i] >> 10;
        atomicAdd(&hist[b], 1);
    }
    __syncthreads();
    if (threadIdx.x == 0) {
        int run = 0;
        for (int b = 0; b < NBK; ++b) { offs[b] = run; run += hist[b]; }
        offs[NBK] = run;
    }
    __syncthreads();
    if (threadIdx.x < NBK) {
        int b = threadIdx.x;
        int h = hist[b];
        if (h > 0) gbase[b] = rowptr[b << 10] + atomicAdd(&gbcur[b << 4], h);
        lcur[b] = offs[b];
    }
    __syncthreads();
    for (int i = threadIdx.x; i < cntE; i += 256) {
        int e = base + i;
        int d = dst[e];
        int b = d >> 10;
        int slot = atomicAdd(&lcur[b], 1);
        stage[slot] = make_int2(src[e], d);
    }
    __syncthreads();
    int total = offs[NBK];
    for (int j = threadIdx.x; j < total; j += 256) {
        int lo = 0, hi = NBK;
        while (lo < hi) { int mid = (lo + hi) >> 1; if (offs[mid + 1] <= j) lo = mid + 1; else hi = mid; }
        pairs[gbase[lo] + (j - offs[lo])] = stage[j];
    }
}

// =============== Phase B: per-128-node tile scatter ===============

__global__ __launch_bounds__(256) void subscatter_kernel(const int2* __restrict__ pairs,
                                                         const int* __restrict__ rowptr,
                                                         int* __restrict__ csr, int N) {
    __shared__ int curs[SUB];
    int sbase = blockIdx.x * SUB;
    int top = min(sbase + SUB, N);
    if (threadIdx.x < top - sbase) curs[threadIdx.x] = rowptr[sbase + threadIdx.x];
    __syncthreads();
    int parent = sbase >> 10;
    int pbeg = rowptr[parent << 10];
    int pend = rowptr[min((parent + 1) << 10, N)];
    for (int j = pbeg + (int)threadIdx.x; j < pend; j += 256) {
        int2 p = pairs[j];
        unsigned local = (unsigned)(p.y - sbase);
        if (local < SUB) {
            int slot = atomicAdd(&curs[local], 1);
            csr[slot] = p.x;
        }
    }
}

// =============== K1: g1 = bf16( (X[N,128] @ W1[128,64]) * dinv ) ===============

__global__ __launch_bounds__(256) void gemm1_kernel(const float* __restrict__ X,
                                                    const float* __restrict__ W,
                                                    const int* __restrict__ rowptr,
                                                    ushort4* __restrict__ gb, int N) {
    __shared__ float Ws[128 * 64];   // 32 KB
    __shared__ float Xs[16][132];
    {
        const float4* Wv = (const float4*)W;
        float4* Wsv = (float4*)Ws;
        for (int i = threadIdx.x; i < 128 * 16; i += 256) Wsv[i] = Wv[i];
    }
    int row = threadIdx.x >> 4;
    int node0 = blockIdx.x * 16;
    int node = node0 + row;
    {
        const float4* Xv = (const float4*)(X + (size_t)node0 * 128);
        for (int i = threadIdx.x; i < 512; i += 256) {
            int r = i >> 5, kk = i & 31;
            if (node0 + r < N) *(float4*)&Xs[r][kk * 4] = Xv[(size_t)r * 32 + kk];
        }
    }
    __syncthreads();
    if (node >= N) return;
    int t = threadIdx.x & 15;
    int c = t * 4;
    float4 acc = make_float4(0.f, 0.f, 0.f, 0.f);
#pragma unroll 16
    for (int k = 0; k < 128; ++k) {
        float xv = Xs[row][k];
        float4 wv = *(const float4*)&Ws[k * 64 + c];
        acc.x += xv * wv.x; acc.y += xv * wv.y;
        acc.z += xv * wv.z; acc.w += xv * wv.w;
    }
    float w = rsqrtf((float)(rowptr[node + 1] - rowptr[node]) + 1.0f);
    gb[(size_t)node * 16 + t] = pack4(acc.x * w, acc.y * w, acc.z * w, acc.w * w);
}

// =============== fused: h = relu(dinv*agg(g) + b); out = bf16((h @ W) * dinv) ===============

__global__ __launch_bounds__(256) void fused_layer_kernel(const ushort4* __restrict__ gb,
                                                          const int* __restrict__ rowptr,
                                                          const int* __restrict__ csr,
                                                          const float* __restrict__ bias,
                                                          const float* __restrict__ W,
                                                          ushort4* __restrict__ out, int N) {
    __shared__ float Ws[64 * 64];    // 16 KB
    __shared__ float T[16][72];
    {
        const float4* Wv = (const float4*)W;
        float4* Wsv = (float4*)Ws;
        for (int i = threadIdx.x; i < 64 * 16; i += 256) Wsv[i] = Wv[i];
    }
    int row = threadIdx.x >> 4;
    int node = blockIdx.x * 16 + row;
    int t = threadIdx.x & 15;
    int c = t * 4;
    float dinv = 0.f;
    if (node < N) {
        int beg = rowptr[node], end = rowptr[node + 1];
        dinv = rsqrtf((float)(end - beg) + 1.0f);
        float4 acc = bf4(gb[(size_t)node * 16 + t]);   // self-loop
        int j = beg;
        for (; j + 8 <= end; j += 8) {
            int s0 = csr[j], s1 = csr[j + 1], s2 = csr[j + 2], s3 = csr[j + 3];
            int s4 = csr[j + 4], s5 = csr[j + 5], s6 = csr[j + 6], s7 = csr[j + 7];
            float4 v0 = bf4(gb[(size_t)s0 * 16 + t]);
            float4 v1 = bf4(gb[(size_t)s1 * 16 + t]);
            float4 v2 = bf4(gb[(size_t)s2 * 16 + t]);
            float4 v3 = bf4(gb[(size_t)s3 * 16 + t]);
            float4 v4 = bf4(gb[(size_t)s4 * 16 + t]);
            float4 v5 = bf4(gb[(size_t)s5 * 16 + t]);
            float4 v6 = bf4(gb[(size_t)s6 * 16 + t]);
            float4 v7 = bf4(gb[(size_t)s7 * 16 + t]);
            acc.x += ((v0.x + v1.x) + (v2.x + v3.x)) + ((v4.x + v5.x) + (v6.x + v7.x));
            acc.y += ((v0.y + v1.y) + (v2.y + v3.y)) + ((v4.y + v5.y) + (v6.y + v7.y));
            acc.z += ((v0.z + v1.z) + (v2.z + v3.z)) + ((v4.z + v5.z) + (v6.z + v7.z));
            acc.w += ((v0.w + v1.w) + (v2.w + v3.w)) + ((v4.w + v5.w) + (v6.w + v7.w));
        }
        for (; j + 2 <= end; j += 2) {
            int s0 = csr[j], s1 = csr[j + 1];
            float4 v0 = bf4(gb[(size_t)s0 * 16 + t]);
            float4 v1 = bf4(gb[(size_t)s1 * 16 + t]);
            acc.x += v0.x + v1.x; acc.y += v0.y + v1.y;
            acc.z += v0.z + v1.z; acc.w += v0.w + v1.w;
        }
        if (j < end) {
            int s0 = csr[j];
            float4 v0 = bf4(gb[(size_t)s0 * 16 + t]);
            acc.x += v0.x; acc.y += v0.y; acc.z += v0.z; acc.w += v0.w;
        }
        float4 bb = *(const float4*)&bias[c];
        T[row][c + 0] = fmaxf(acc.x * dinv + bb.x, 0.f);
        T[row][c + 1] = fmaxf(acc.y * dinv + bb.y, 0.f);
        T[row][c + 2] = fmaxf(acc.z * dinv + bb.z, 0.f);
        T[row][c + 3] = fmaxf(acc.w * dinv + bb.w, 0.f);
    }
    __syncthreads();
    if (node >= N) return;
    float4 o = make_float4(0.f, 0.f, 0.f, 0.f);
#pragma unroll 16
    for (int k = 0; k < 64; ++k) {
        float tv = T[row][k];
        float4 wv = *(const float4*)&Ws[k * 64 + c];
        o.x += tv * wv.x; o.y += tv * wv.y;
        o.z += tv * wv.z; o.w += tv * wv.w;
    }
    out[(size_t)node * 16 + t] = pack4(o.x * dinv, o.y * dinv, o.z * dinv, o.w * dinv);
}

// =============== K4: h3 = dinv*agg(g3) + b3;  s_node = h3 . Wl ===============

__global__ __launch_bounds__(256) void agg_dot_kernel(const ushort4* __restrict__ gb,
                                                      const int* __restrict__ rowptr,
                                                      const int* __restrict__ csr,
                                                      const float* __restrict__ bias,
                                                      const float* __restrict__ Wl,
                                                      float* __restrict__ s_node, int N) {
    int tid = blockIdx.x * blockDim.x + threadIdx.x;
    int node = tid >> 4;
    if (node >= N) return;
    int t = tid & 15;
    int beg = rowptr[node], end = rowptr[node + 1];
    float dinv = rsqrtf((float)(end - beg) + 1.0f);
    float4 acc = bf4(gb[(size_t)node * 16 + t]);
    int j = beg;
    for (; j + 8 <= end; j += 8) {
        int s0 = csr[j], s1 = csr[j + 1], s2 = csr[j + 2], s3 = csr[j + 3];
        int s4 = csr[j + 4], s5 = csr[j + 5], s6 = csr[j + 6], s7 = csr[j + 7];
        float4 v0 = bf4(gb[(size_t)s0 * 16 + t]);
        float4 v1 = bf4(gb[(size_t)s1 * 16 + t]);
        float4 v2 = bf4(gb[(size_t)s2 * 16 + t]);
        float4 v3 = bf4(gb[(size_t)s3 * 16 + t]);
        float4 v4 = bf4(gb[(size_t)s4 * 16 + t]);
        float4 v5 = bf4(gb[(size_t)s5 * 16 + t]);
        float4 v6 = bf4(gb[(size_t)s6 * 16 + t]);
        float4 v7 = bf4(gb[(size_t)s7 * 16 + t]);
        acc.x += ((v0.x + v1.x) + (v2.x + v3.x)) + ((v4.x + v5.x) + (v6.x + v7.x));
        acc.y += ((v0.y + v1.y) + (v2.y + v3.y)) + ((v4.y + v5.y) + (v6.y + v7.y));
        acc.z += ((v0.z + v1.z) + (v2.z + v3.z)) + ((v4.z + v5.z) + (v6.z + v7.z));
        acc.w += ((v0.w + v1.w) + (v2.w + v3.w)) + ((v4.w + v5.w) + (v6.w + v7.w));
    }
    for (; j + 2 <= end; j += 2) {
        int s0 = csr[j], s1 = csr[j + 1];
        float4 v0 = bf4(gb[(size_t)s0 * 16 + t]);
        float4 v1 = bf4(gb[(size_t)s1 * 16 + t]);
        acc.x += v0.x + v1.x; acc.y += v0.y + v1.y;
        acc.z += v0.z + v1.z; acc.w += v0.w + v1.w;
    }
    if (j < end) {
        int s0 = csr[j];
        float4 v0 = bf4(gb[(size_t)s0 * 16 + t]);
        acc.x += v0.x; acc.y += v0.y; acc.z += v0.z; acc.w += v0.w;
    }
    float4 bb = *(const float4*)&bias[t * 4];
    float4 wl = *(const float4*)&Wl[t * 4];
    float s = (acc.x * dinv + bb.x) * wl.x + (acc.y * dinv + bb.y) * wl.y +
              (acc.z * dinv + bb.z) * wl.z + (acc.w * dinv + bb.w) * wl.w;
    s += __shfl_xor(s, 1);
    s += __shfl_xor(s, 2);
    s += __shfl_xor(s, 4);
    s += __shfl_xor(s, 8);
    if (t == 0) s_node[node] = s;
}

// =============== K5: per-graph mean over sorted batch + bl ===============

__device__ __forceinline__ int lower_bound_dev(const int* __restrict__ a, int n, int v) {
    int lo = 0, hi = n;
    while (lo < hi) { int mid = (lo + hi) >> 1; if (a[mid] < v) lo = mid + 1; else hi = mid; }
    return lo;
}

__global__ void pool_out_kernel(const float* __restrict__ s_node, const int* __restrict__ batch,
                                const float* __restrict__ bl, float* __restrict__ out, int N) {
    int gidx = blockIdx.x;
    int lo = lower_bound_dev(batch, N, gidx);
    int hi = lower_bound_dev(batch, N, gidx + 1);
    float s = 0.f;
    for (int i = lo + threadIdx.x; i < hi; i += 64) s += s_node[i];
    for (int d = 32; d; d >>= 1) s += __shfl_down(s, d);
    if (threadIdx.x == 0) out[gidx] = s / fmaxf((float)(hi - lo), 1.0f) + bl[0];
}

// =============== launcher ===============

extern "C" void kernel_launch(void* const* d_in, const int* in_sizes, int n_in,
                              void* d_out, int out_size, void* d_ws, size_t ws_size,
                              hipStream_t stream) {
    const float* x   = (const float*)d_in[0];
    const int*   ei  = (const int*)d_in[1];
    const int*   bat = (const int*)d_in[2];
    const float* W1  = (const float*)d_in[3];
    const float* b1  = (const float*)d_in[4];
    const float* W2  = (const float*)d_in[5];
    const float* b2  = (const float*)d_in[6];
    const float* W3  = (const float*)d_in[7];
    const float* b3  = (const float*)d_in[8];
    const float* Wl  = (const float*)d_in[9];
    const float* bl  = (const float*)d_in[10];

    const int N = in_sizes[0] / 128;   // 100000
    const int E = in_sizes[1] / 2;     // 1600000
    const int G = out_size;            // 1000

    const int* src = ei;
    const int* dst = ei + E;

    const int NBK  = (N + BKT - 1) / BKT;      // coarse buckets (98)
    const int NSUB = (N + SUB - 1) / SUB;      // fine tiles (782)
    const int Np = (N + 4) & ~3;

    // workspace layout (all segments 8B-aligned; ~46 MB total)
    int*     cnt    = (int*)d_ws;                  // N : hist -> (later) s_node
    int*     rowptr = cnt + N;                     // Np
    int*     sums   = rowptr + Np;                 // 1024
    int*     gbcur  = sums + 1024;                 // NBK*16 padded cursors
    int*     csr    = gbcur + (size_t)NBK * 16;    // E
    int2*    pairs  = (int2*)(csr + E);            // E
    ushort4* gbA    = (ushort4*)(pairs + E);       // N*16 (bf16 features)
    ushort4* gbB    = gbA + (size_t)N * 16;        // N*16
    float*   s_node = (float*)cnt;

    const int nb = (N + 1023) / 1024;

    // ---- rowptr ----
    hipMemsetAsync(cnt, 0, (size_t)N * sizeof(int), stream);
    hipMemsetAsync(gbcur, 0, (size_t)NBK * 16 * sizeof(int), stream);
    hist_kernel<<<(E + 255) / 256, 256, 0, stream>>>(dst, cnt, E);
    scan_sums<<<nb, 256, 0, stream>>>(cnt, sums, N);
    scan_offsets<<<1, 64, 0, stream>>>(sums, nb);
    scan_write<<<nb, 256, 0, stream>>>(cnt, sums, rowptr, N, E);

    // ---- two-phase CSR fill ----
    partition_kernel<<<(E + EPB - 1) / EPB, 256, 0, stream>>>(src, dst, rowptr, gbcur, pairs, E, NBK);
    subscatter_kernel<<<NSUB, 256, 0, stream>>>(pairs, rowptr, csr, N);

    const int tileGrid = (N + 15) / 16;
    const int aggGrid  = (int)(((size_t)N * 16 + 255) / 256);

    gemm1_kernel<<<tileGrid, 256, 0, stream>>>(x, W1, rowptr, gbA, N);
    fused_layer_kernel<<<tileGrid, 256, 0, stream>>>(gbA, rowptr, csr, b1, W2, gbB, N);
    fused_layer_kernel<<<tileGrid, 256, 0, stream>>>(gbB, rowptr, csr, b2, W3, gbA, N);
    agg_dot_kernel<<<aggGrid, 256, 0, stream>>>(gbA, rowptr, csr, b3, Wl, s_node, N);
    pool_out_kernel<<<G, 64, 0, stream>>>(s_node, bat, bl, (float*)d_out, N);
}

// Round 10
// 311.814 us; speedup vs baseline: 2.2289x; 1.1986x over previous
//
#include <hip/hip_runtime.h>
#include <stdint.h>

#define BKT 1024   // nodes per coarse bucket
#define EPB 4096   // edges per partition block

// ---- bf16 helpers (RNE pack, exact expand) ----
__device__ __forceinline__ unsigned short f2bf(float f) {
    unsigned u = __float_as_uint(f);
    u = u + 0x7FFFu + ((u >> 16) & 1u);
    return (unsigned short)(u >> 16);
}
__device__ __forceinline__ float bf2f(unsigned short h) {
    return __uint_as_float(((unsigned)h) << 16);
}
__device__ __forceinline__ float4 bf4(ushort4 v) {
    return make_float4(bf2f(v.x), bf2f(v.y), bf2f(v.z), bf2f(v.w));
}
__device__ __forceinline__ ushort4 pack4(float a, float b, float c, float d) {
    ushort4 r; r.x = f2bf(a); r.y = f2bf(b); r.z = f2bf(c); r.w = f2bf(d); return r;
}

// =============== coarse (98-bin) histogram: LDS-reduced ===============

__global__ __launch_bounds__(256) void coarse_hist(const int* __restrict__ dst,
                                                   int* __restrict__ coarse, int E, int NBK) {
    __shared__ int h[128];
    if (threadIdx.x < 128) h[threadIdx.x] = 0;
    __syncthreads();
    int stride = gridDim.x * 256;
    for (int i = blockIdx.x * 256 + threadIdx.x; i < E; i += stride)
        atomicAdd(&h[dst[i] >> 10], 1);
    __syncthreads();
    if (threadIdx.x < NBK) {
        int v = h[threadIdx.x];
        if (v) atomicAdd(&coarse[threadIdx.x], v);
    }
}

__global__ void coarse_scan(const int* __restrict__ coarse, int* __restrict__ bbase,
                            int NBK, int E) {
    if (threadIdx.x == 0 && blockIdx.x == 0) {
        int run = 0;
        for (int i = 0; i < NBK; ++i) { bbase[i] = run; run += coarse[i]; }
        bbase[NBK] = E;
    }
}

// =============== Phase A: LDS-staged counting-sort partition by dst>>10 ===============

__global__ __launch_bounds__(256) void partition_kernel(const int* __restrict__ src,
                                                        const int* __restrict__ dst,
                                                        const int* __restrict__ bbase,
                                                        int* __restrict__ gbcur,
                                                        int2* __restrict__ pairs,
                                                        int E, int NBK) {
    __shared__ int2 stage[EPB];          // 32 KB
    __shared__ int  hist[128], offs[129], gbase[128], lcur[128];
    int base = blockIdx.x * EPB;
    int cntE = min(EPB, E - base);
    if (threadIdx.x < 128) hist[threadIdx.x] = 0;
    __syncthreads();
    for (int i = threadIdx.x; i < cntE; i += 256) {
        int b = dst[base + i] >> 10;
        atomicAdd(&hist[b], 1);
    }
    __syncthreads();
    if (threadIdx.x == 0) {
        int run = 0;
        for (int b = 0; b < NBK; ++b) { offs[b] = run; run += hist[b]; }
        offs[NBK] = run;
    }
    __syncthreads();
    if (threadIdx.x < NBK) {
        int b = threadIdx.x;
        int h = hist[b];
        if (h > 0) gbase[b] = bbase[b] + atomicAdd(&gbcur[b << 4], h);
        lcur[b] = offs[b];
    }
    __syncthreads();
    for (int i = threadIdx.x; i < cntE; i += 256) {
        int e = base + i;
        int d = dst[e];
        int b = d >> 10;
        int slot = atomicAdd(&lcur[b], 1);
        stage[slot] = make_int2(src[e], d);
    }
    __syncthreads();
    int total = offs[NBK];
    for (int j = threadIdx.x; j < total; j += 256) {
        int lo = 0, hi = NBK;
        while (lo < hi) { int mid = (lo + hi) >> 1; if (offs[mid + 1] <= j) lo = mid + 1; else hi = mid; }
        pairs[gbase[lo] + (j - offs[lo])] = stage[j];
    }
}

// =============== Phase B: per-bucket hist + scan -> rowptr, then scatter -> csr ===============

__global__ __launch_bounds__(256) void bucket_build(const int2* __restrict__ pairs,
                                                    const int* __restrict__ bbase,
                                                    int* __restrict__ rowptr,
                                                    int* __restrict__ csr, int N, int E) {
    __shared__ int cnt[BKT];      // counters -> cursors
    __shared__ int psum[256];
    int b = blockIdx.x;
    int nbase = b << 10;
    int pbeg = bbase[b], pend = bbase[b + 1];
    for (int i = threadIdx.x; i < BKT; i += 256) cnt[i] = 0;
    __syncthreads();
    // pass 1: per-node counts (LDS atomics)
    for (int j = pbeg + (int)threadIdx.x; j < pend; j += 256)
        atomicAdd(&cnt[pairs[j].y - nbase], 1);
    __syncthreads();
    // scan: each thread owns 4 consecutive counters
    int i0 = threadIdx.x * 4;
    int c0 = cnt[i0], c1 = cnt[i0 + 1], c2 = cnt[i0 + 2], c3 = cnt[i0 + 3];
    int local = c0 + c1 + c2 + c3;
    psum[threadIdx.x] = local;
    __syncthreads();
    for (int d = 1; d < 256; d <<= 1) {
        int t = (threadIdx.x >= d) ? psum[threadIdx.x - d] : 0;
        __syncthreads();
        psum[threadIdx.x] += t;
        __syncthreads();
    }
    int excl = psum[threadIdx.x] - local;
    int o0 = pbeg + excl;
    int o1 = o0 + c0, o2 = o1 + c1, o3 = o2 + c2;
    int n0 = nbase + i0;
    if (n0 < N)     rowptr[n0]     = o0;
    if (n0 + 1 < N) rowptr[n0 + 1] = o1;
    if (n0 + 2 < N) rowptr[n0 + 2] = o2;
    if (n0 + 3 < N) rowptr[n0 + 3] = o3;
    cnt[i0] = o0; cnt[i0 + 1] = o1; cnt[i0 + 2] = o2; cnt[i0 + 3] = o3;
    __syncthreads();
    // pass 2: scatter
    for (int j = pbeg + (int)threadIdx.x; j < pend; j += 256) {
        int2 p = pairs[j];
        int slot = atomicAdd(&cnt[p.y - nbase], 1);
        csr[slot] = p.x;
    }
    if (b == 0 && threadIdx.x == 0) rowptr[N] = E;
}

// =============== K1: g1 = bf16( (X[N,128] @ W1[128,64]) * dinv ) ===============

__global__ __launch_bounds__(256) void gemm1_kernel(const float* __restrict__ X,
                                                    const float* __restrict__ W,
                                                    const int* __restrict__ rowptr,
                                                    ushort4* __restrict__ gb, int N) {
    __shared__ float Ws[128 * 64];   // 32 KB
    __shared__ float Xs[16][132];
    {
        const float4* Wv = (const float4*)W;
        float4* Wsv = (float4*)Ws;
        for (int i = threadIdx.x; i < 128 * 16; i += 256) Wsv[i] = Wv[i];
    }
    int row = threadIdx.x >> 4;
    int node0 = blockIdx.x * 16;
    int node = node0 + row;
    {
        const float4* Xv = (const float4*)(X + (size_t)node0 * 128);
        for (int i = threadIdx.x; i < 512; i += 256) {
            int r = i >> 5, kk = i & 31;
            if (node0 + r < N) *(float4*)&Xs[r][kk * 4] = Xv[(size_t)r * 32 + kk];
        }
    }
    __syncthreads();
    if (node >= N) return;
    int t = threadIdx.x & 15;
    int c = t * 4;
    float4 acc = make_float4(0.f, 0.f, 0.f, 0.f);
#pragma unroll 16
    for (int k = 0; k < 128; ++k) {
        float xv = Xs[row][k];
        float4 wv = *(const float4*)&Ws[k * 64 + c];
        acc.x += xv * wv.x; acc.y += xv * wv.y;
        acc.z += xv * wv.z; acc.w += xv * wv.w;
    }
    float w = rsqrtf((float)(rowptr[node + 1] - rowptr[node]) + 1.0f);
    gb[(size_t)node * 16 + t] = pack4(acc.x * w, acc.y * w, acc.z * w, acc.w * w);
}

// =============== fused: h = relu(dinv*agg(g) + b); out = bf16((h @ W) * dinv) ===============

__global__ __launch_bounds__(256) void fused_layer_kernel(const ushort4* __restrict__ gb,
                                                          const int* __restrict__ rowptr,
                                                          const int* __restrict__ csr,
                                                          const float* __restrict__ bias,
                                                          const float* __restrict__ W,
                                                          ushort4* __restrict__ out, int N) {
    __shared__ float Ws[64 * 64];    // 16 KB
    __shared__ float T[16][72];
    {
        const float4* Wv = (const float4*)W;
        float4* Wsv = (float4*)Ws;
        for (int i = threadIdx.x; i < 64 * 16; i += 256) Wsv[i] = Wv[i];
    }
    int row = threadIdx.x >> 4;
    int node = blockIdx.x * 16 + row;
    int t = threadIdx.x & 15;
    int c = t * 4;
    float dinv = 0.f;
    if (node < N) {
        int beg = rowptr[node], end = rowptr[node + 1];
        dinv = rsqrtf((float)(end - beg) + 1.0f);
        float4 acc = bf4(gb[(size_t)node * 16 + t]);   // self-loop
        int j = beg;
        for (; j + 8 <= end; j += 8) {
            int s0 = csr[j], s1 = csr[j + 1], s2 = csr[j + 2], s3 = csr[j + 3];
            int s4 = csr[j + 4], s5 = csr[j + 5], s6 = csr[j + 6], s7 = csr[j + 7];
            float4 v0 = bf4(gb[(size_t)s0 * 16 + t]);
            float4 v1 = bf4(gb[(size_t)s1 * 16 + t]);
            float4 v2 = bf4(gb[(size_t)s2 * 16 + t]);
            float4 v3 = bf4(gb[(size_t)s3 * 16 + t]);
            float4 v4 = bf4(gb[(size_t)s4 * 16 + t]);
            float4 v5 = bf4(gb[(size_t)s5 * 16 + t]);
            float4 v6 = bf4(gb[(size_t)s6 * 16 + t]);
            float4 v7 = bf4(gb[(size_t)s7 * 16 + t]);
            acc.x += ((v0.x + v1.x) + (v2.x + v3.x)) + ((v4.x + v5.x) + (v6.x + v7.x));
            acc.y += ((v0.y + v1.y) + (v2.y + v3.y)) + ((v4.y + v5.y) + (v6.y + v7.y));
            acc.z += ((v0.z + v1.z) + (v2.z + v3.z)) + ((v4.z + v5.z) + (v6.z + v7.z));
            acc.w += ((v0.w + v1.w) + (v2.w + v3.w)) + ((v4.w + v5.w) + (v6.w + v7.w));
        }
        for (; j + 2 <= end; j += 2) {
            int s0 = csr[j], s1 = csr[j + 1];
            float4 v0 = bf4(gb[(size_t)s0 * 16 + t]);
            float4 v1 = bf4(gb[(size_t)s1 * 16 + t]);
            acc.x += v0.x + v1.x; acc.y += v0.y + v1.y;
            acc.z += v0.z + v1.z; acc.w += v0.w + v1.w;
        }
        if (j < end) {
            int s0 = csr[j];
            float4 v0 = bf4(gb[(size_t)s0 * 16 + t]);
            acc.x += v0.x; acc.y += v0.y; acc.z += v0.z; acc.w += v0.w;
        }
        float4 bb = *(const float4*)&bias[c];
        T[row][c + 0] = fmaxf(acc.x * dinv + bb.x, 0.f);
        T[row][c + 1] = fmaxf(acc.y * dinv + bb.y, 0.f);
        T[row][c + 2] = fmaxf(acc.z * dinv + bb.z, 0.f);
        T[row][c + 3] = fmaxf(acc.w * dinv + bb.w, 0.f);
    }
    __syncthreads();
    if (node >= N) return;
    float4 o = make_float4(0.f, 0.f, 0.f, 0.f);
#pragma unroll 16
    for (int k = 0; k < 64; ++k) {
        float tv = T[row][k];
        float4 wv = *(const float4*)&Ws[k * 64 + c];
        o.x += tv * wv.x; o.y += tv * wv.y;
        o.z += tv * wv.z; o.w += tv * wv.w;
    }
    out[(size_t)node * 16 + t] = pack4(o.x * dinv, o.y * dinv, o.z * dinv, o.w * dinv);
}

// =============== K4: h3 = dinv*agg(g3) + b3;  s_node = h3 . Wl ===============

__global__ __launch_bounds__(256) void agg_dot_kernel(const ushort4* __restrict__ gb,
                                                      const int* __restrict__ rowptr,
                                                      const int* __restrict__ csr,
                                                      const float* __restrict__ bias,
                                                      const float* __restrict__ Wl,
                                                      float* __restrict__ s_node, int N) {
    int tid = blockIdx.x * blockDim.x + threadIdx.x;
    int node = tid >> 4;
    if (node >= N) return;
    int t = tid & 15;
    int beg = rowptr[node], end = rowptr[node + 1];
    float dinv = rsqrtf((float)(end - beg) + 1.0f);
    float4 acc = bf4(gb[(size_t)node * 16 + t]);
    int j = beg;
    for (; j + 8 <= end; j += 8) {
        int s0 = csr[j], s1 = csr[j + 1], s2 = csr[j + 2], s3 = csr[j + 3];
        int s4 = csr[j + 4], s5 = csr[j + 5], s6 = csr[j + 6], s7 = csr[j + 7];
        float4 v0 = bf4(gb[(size_t)s0 * 16 + t]);
        float4 v1 = bf4(gb[(size_t)s1 * 16 + t]);
        float4 v2 = bf4(gb[(size_t)s2 * 16 + t]);
        float4 v3 = bf4(gb[(size_t)s3 * 16 + t]);
        float4 v4 = bf4(gb[(size_t)s4 * 16 + t]);
        float4 v5 = bf4(gb[(size_t)s5 * 16 + t]);
        float4 v6 = bf4(gb[(size_t)s6 * 16 + t]);
        float4 v7 = bf4(gb[(size_t)s7 * 16 + t]);
        acc.x += ((v0.x + v1.x) + (v2.x + v3.x)) + ((v4.x + v5.x) + (v6.x + v7.x));
        acc.y += ((v0.y + v1.y) + (v2.y + v3.y)) + ((v4.y + v5.y) + (v6.y + v7.y));
        acc.z += ((v0.z + v1.z) + (v2.z + v3.z)) + ((v4.z + v5.z) + (v6.z + v7.z));
        acc.w += ((v0.w + v1.w) + (v2.w + v3.w)) + ((v4.w + v5.w) + (v6.w + v7.w));
    }
    for (; j + 2 <= end; j += 2) {
        int s0 = csr[j], s1 = csr[j + 1];
        float4 v0 = bf4(gb[(size_t)s0 * 16 + t]);
        float4 v1 = bf4(gb[(size_t)s1 * 16 + t]);
        acc.x += v0.x + v1.x; acc.y += v0.y + v1.y;
        acc.z += v0.z + v1.z; acc.w += v0.w + v1.w;
    }
    if (j < end) {
        int s0 = csr[j];
        float4 v0 = bf4(gb[(size_t)s0 * 16 + t]);
        acc.x += v0.x; acc.y += v0.y; acc.z += v0.z; acc.w += v0.w;
    }
    float4 bb = *(const float4*)&bias[t * 4];
    float4 wl = *(const float4*)&Wl[t * 4];
    float s = (acc.x * dinv + bb.x) * wl.x + (acc.y * dinv + bb.y) * wl.y +
              (acc.z * dinv + bb.z) * wl.z + (acc.w * dinv + bb.w) * wl.w;
    s += __shfl_xor(s, 1);
    s += __shfl_xor(s, 2);
    s += __shfl_xor(s, 4);
    s += __shfl_xor(s, 8);
    if (t == 0) s_node[node] = s;
}

// =============== K5: per-graph mean over sorted batch + bl ===============

__device__ __forceinline__ int lower_bound_dev(const int* __restrict__ a, int n, int v) {
    int lo = 0, hi = n;
    while (lo < hi) { int mid = (lo + hi) >> 1; if (a[mid] < v) lo = mid + 1; else hi = mid; }
    return lo;
}

__global__ void pool_out_kernel(const float* __restrict__ s_node, const int* __restrict__ batch,
                                const float* __restrict__ bl, float* __restrict__ out, int N) {
    int gidx = blockIdx.x;
    int lo = lower_bound_dev(batch, N, gidx);
    int hi = lower_bound_dev(batch, N, gidx + 1);
    float s = 0.f;
    for (int i = lo + threadIdx.x; i < hi; i += 64) s += s_node[i];
    for (int d = 32; d; d >>= 1) s += __shfl_down(s, d);
    if (threadIdx.x == 0) out[gidx] = s / fmaxf((float)(hi - lo), 1.0f) + bl[0];
}

// =============== launcher ===============

extern "C" void kernel_launch(void* const* d_in, const int* in_sizes, int n_in,
                              void* d_out, int out_size, void* d_ws, size_t ws_size,
                              hipStream_t stream) {
    const float* x   = (const float*)d_in[0];
    const int*   ei  = (const int*)d_in[1];
    const int*   bat = (const int*)d_in[2];
    const float* W1  = (const float*)d_in[3];
    const float* b1  = (const float*)d_in[4];
    const float* W2  = (const float*)d_in[5];
    const float* b2  = (const float*)d_in[6];
    const float* W3  = (const float*)d_in[7];
    const float* b3  = (const float*)d_in[8];
    const float* Wl  = (const float*)d_in[9];
    const float* bl  = (const float*)d_in[10];

    const int N = in_sizes[0] / 128;   // 100000
    const int E = in_sizes[1] / 2;     // 1600000
    const int G = out_size;            // 1000

    const int* src = ei;
    const int* dst = ei + E;

    const int NBK = (N + BKT - 1) / BKT;       // coarse buckets (98)
    const int Np = (N + 4) & ~3;

    // workspace layout
    int*     rowptr = (int*)d_ws;                  // Np
    int*     coarse = rowptr + Np;                 // 128
    int*     bbase  = coarse + 128;                // 132 (NBK+1, padded)
    int*     gbcur  = bbase + 132;                 // NBK*16 padded cursors
    int*     csr    = gbcur + (size_t)NBK * 16;    // E
    int2*    pairs  = (int2*)(csr + E);            // E
    ushort4* gbA    = (ushort4*)(pairs + E);       // N*16 (bf16 features)
    ushort4* gbB    = gbA + (size_t)N * 16;        // N*16
    float*   s_node = (float*)(gbB + (size_t)N * 16);  // N

    // ---- CSR build ----
    hipMemsetAsync(coarse, 0, (260 + (size_t)NBK * 16) * sizeof(int), stream);
    coarse_hist<<<256, 256, 0, stream>>>(dst, coarse, E, NBK);
    coarse_scan<<<1, 64, 0, stream>>>(coarse, bbase, NBK, E);
    partition_kernel<<<(E + EPB - 1) / EPB, 256, 0, stream>>>(src, dst, bbase, gbcur, pairs, E, NBK);
    bucket_build<<<NBK, 256, 0, stream>>>(pairs, bbase, rowptr, csr, N, E);

    const int tileGrid = (N + 15) / 16;
    const int aggGrid  = (int)(((size_t)N * 16 + 255) / 256);

    gemm1_kernel<<<tileGrid, 256, 0, stream>>>(x, W1, rowptr, gbA, N);
    fused_layer_kernel<<<tileGrid, 256, 0, stream>>>(gbA, rowptr, csr, b1, W2, gbB, N);
    fused_layer_kernel<<<tileGrid, 256, 0, stream>>>(gbB, rowptr, csr, b2, W3, gbA, N);
    agg_dot_kernel<<<aggGrid, 256, 0, stream>>>(gbA, rowptr, csr, b3, Wl, s_node, N);
    pool_out_kernel<<<G, 64, 0, stream>>>(s_node, bat, bl, (float*)d_out, N);
}

// Round 11
// 280.226 us; speedup vs baseline: 2.4801x; 1.1127x over previous
//
#include <hip/hip_runtime.h>
#include <stdint.h>

#define BKT 1024   // nodes per coarse bucket
#define EPB 4096   // edges per partition block

typedef __attribute__((ext_vector_type(8))) __bf16 bf16x8;
typedef __attribute__((ext_vector_type(4))) float floatx4;

// ---- bf16 helpers (RNE pack, exact expand) ----
__device__ __forceinline__ float bf2f(unsigned short h) {
    return __uint_as_float(((unsigned)h) << 16);
}
__device__ __forceinline__ float4 bf4(ushort4 v) {
    return make_float4(bf2f(v.x), bf2f(v.y), bf2f(v.z), bf2f(v.w));
}
__device__ __forceinline__ unsigned short f2bf(float f) {
    unsigned u = __float_as_uint(f);
    u = u + 0x7FFFu + ((u >> 16) & 1u);
    return (unsigned short)(u >> 16);
}
__device__ __forceinline__ ushort4 pack4(float a, float b, float c, float d) {
    ushort4 r; r.x = f2bf(a); r.y = f2bf(b); r.z = f2bf(c); r.w = f2bf(d); return r;
}

// =============== coarse (98-bin) histogram: LDS-reduced ===============

__global__ __launch_bounds__(256) void coarse_hist(const int* __restrict__ dst,
                                                   int* __restrict__ coarse, int E, int NBK) {
    __shared__ int h[128];
    if (threadIdx.x < 128) h[threadIdx.x] = 0;
    __syncthreads();
    int stride = gridDim.x * 256;
    for (int i = blockIdx.x * 256 + threadIdx.x; i < E; i += stride)
        atomicAdd(&h[dst[i] >> 10], 1);
    __syncthreads();
    if (threadIdx.x < NBK) {
        int v = h[threadIdx.x];
        if (v) atomicAdd(&coarse[threadIdx.x], v);
    }
}

__global__ void coarse_scan(const int* __restrict__ coarse, int* __restrict__ bbase,
                            int NBK, int E) {
    if (threadIdx.x == 0 && blockIdx.x == 0) {
        int run = 0;
        for (int i = 0; i < NBK; ++i) { bbase[i] = run; run += coarse[i]; }
        bbase[NBK] = E;
    }
}

// =============== Phase A: LDS-staged counting-sort partition by dst>>10 ===============

__global__ __launch_bounds__(256) void partition_kernel(const int* __restrict__ src,
                                                        const int* __restrict__ dst,
                                                        const int* __restrict__ bbase,
                                                        int* __restrict__ gbcur,
                                                        int2* __restrict__ pairs,
                                                        int E, int NBK) {
    __shared__ int2 stage[EPB];          // 32 KB
    __shared__ int  hist[128], offs[129], gbase[128], lcur[128];
    int base = blockIdx.x * EPB;
    int cntE = min(EPB, E - base);
    if (threadIdx.x < 128) hist[threadIdx.x] = 0;
    __syncthreads();
    for (int i = threadIdx.x; i < cntE; i += 256) {
        int b = dst[base + i] >> 10;
        atomicAdd(&hist[b], 1);
    }
    __syncthreads();
    if (threadIdx.x == 0) {
        int run = 0;
        for (int b = 0; b < NBK; ++b) { offs[b] = run; run += hist[b]; }
        offs[NBK] = run;
    }
    __syncthreads();
    if (threadIdx.x < NBK) {
        int b = threadIdx.x;
        int h = hist[b];
        if (h > 0) gbase[b] = bbase[b] + atomicAdd(&gbcur[b << 4], h);
        lcur[b] = offs[b];
    }
    __syncthreads();
    for (int i = threadIdx.x; i < cntE; i += 256) {
        int e = base + i;
        int d = dst[e];
        int b = d >> 10;
        int slot = atomicAdd(&lcur[b], 1);
        stage[slot] = make_int2(src[e], d);
    }
    __syncthreads();
    int total = offs[NBK];
    for (int j = threadIdx.x; j < total; j += 256) {
        int lo = 0, hi = NBK;
        while (lo < hi) { int mid = (lo + hi) >> 1; if (offs[mid + 1] <= j) lo = mid + 1; else hi = mid; }
        pairs[gbase[lo] + (j - offs[lo])] = stage[j];
    }
}

// =============== Phase B: per-bucket hist + scan -> rowptr, then scatter -> csr ===============

__global__ __launch_bounds__(256) void bucket_build(const int2* __restrict__ pairs,
                                                    const int* __restrict__ bbase,
                                                    int* __restrict__ rowptr,
                                                    int* __restrict__ csr, int N, int E) {
    __shared__ int cnt[BKT];      // counters -> cursors
    __shared__ int psum[256];
    int b = blockIdx.x;
    int nbase = b << 10;
    int pbeg = bbase[b], pend = bbase[b + 1];
    for (int i = threadIdx.x; i < BKT; i += 256) cnt[i] = 0;
    __syncthreads();
    for (int j = pbeg + (int)threadIdx.x; j < pend; j += 256)
        atomicAdd(&cnt[pairs[j].y - nbase], 1);
    __syncthreads();
    int i0 = threadIdx.x * 4;
    int c0 = cnt[i0], c1 = cnt[i0 + 1], c2 = cnt[i0 + 2], c3 = cnt[i0 + 3];
    int local = c0 + c1 + c2 + c3;
    psum[threadIdx.x] = local;
    __syncthreads();
    for (int d = 1; d < 256; d <<= 1) {
        int t = (threadIdx.x >= d) ? psum[threadIdx.x - d] : 0;
        __syncthreads();
        psum[threadIdx.x] += t;
        __syncthreads();
    }
    int excl = psum[threadIdx.x] - local;
    int o0 = pbeg + excl;
    int o1 = o0 + c0, o2 = o1 + c1, o3 = o2 + c2;
    int n0 = nbase + i0;
    if (n0 < N)     rowptr[n0]     = o0;
    if (n0 + 1 < N) rowptr[n0 + 1] = o1;
    if (n0 + 2 < N) rowptr[n0 + 2] = o2;
    if (n0 + 3 < N) rowptr[n0 + 3] = o3;
    cnt[i0] = o0; cnt[i0 + 1] = o1; cnt[i0 + 2] = o2; cnt[i0 + 3] = o3;
    __syncthreads();
    for (int j = pbeg + (int)threadIdx.x; j < pend; j += 256) {
        int2 p = pairs[j];
        int slot = atomicAdd(&cnt[p.y - nbase], 1);
        csr[slot] = p.x;
    }
    if (b == 0 && threadIdx.x == 0) rowptr[N] = E;
}

// =============== K1 (MFMA): g1 = bf16( (X[N,128] @ W1[128,64]) * dinv ) ===============
// Block = 64 nodes, 4 waves; wave = 16 rows x 64 cols.
// A-frags from global (row = lane&15, k = (lane>>4)*8+j, contiguous);
// B staged transposed bf16 in LDS (col = lane&15, same k grouping);
// C/D: col = lane&15, row = (lane>>4)*4+reg  [m89].

__global__ __launch_bounds__(256) void gemm1_mfma(const float* __restrict__ X,
                                                  const float* __restrict__ W,
                                                  const int* __restrict__ rowptr,
                                                  __bf16* __restrict__ gbh, int N) {
    __shared__ __align__(16) __bf16 Wt[64][136];   // transposed, padded: ~2-way conflicts (free)
    for (int i = threadIdx.x; i < 128 * 64; i += 256) {
        int k = i >> 6, c = i & 63;
        Wt[c][k] = (__bf16)W[i];
    }
    __syncthreads();

    int wave = threadIdx.x >> 6;
    int l = threadIdx.x & 63;
    int cidx = l & 15;
    int g = l >> 4;
    int wbase = blockIdx.x * 64 + wave * 16;

    // ---- A fragments: X[arow][kb*32 + g*8 .. +7], fp32 -> bf16 ----
    int arow = wbase + cidx;
    int arowc = min(arow, N - 1);
    const float4* xr = (const float4*)(X + (size_t)arowc * 128);
    bf16x8 afr[4];
#pragma unroll
    for (int kb = 0; kb < 4; ++kb) {
        float4 p = xr[kb * 8 + g * 2];
        float4 q = xr[kb * 8 + g * 2 + 1];
        bf16x8 a;
        a[0] = (__bf16)p.x; a[1] = (__bf16)p.y; a[2] = (__bf16)p.z; a[3] = (__bf16)p.w;
        a[4] = (__bf16)q.x; a[5] = (__bf16)q.y; a[6] = (__bf16)q.z; a[7] = (__bf16)q.w;
        afr[kb] = a;
    }

    floatx4 acc[4];
#pragma unroll
    for (int ct = 0; ct < 4; ++ct) acc[ct] = (floatx4){0.f, 0.f, 0.f, 0.f};

#pragma unroll
    for (int ct = 0; ct < 4; ++ct) {
#pragma unroll
        for (int kb = 0; kb < 4; ++kb) {
            bf16x8 bfr = *(const bf16x8*)&Wt[ct * 16 + cidx][kb * 32 + g * 8];
            acc[ct] = __builtin_amdgcn_mfma_f32_16x16x32_bf16(afr[kb], bfr, acc[ct], 0, 0, 0);
        }
    }

    // ---- epilogue: scale rows by dinv, store bf16 ----
    int r0 = wbase + g * 4;
    int rp[5];
#pragma unroll
    for (int i = 0; i < 5; ++i) rp[i] = rowptr[min(r0 + i, N)];
#pragma unroll
    for (int i = 0; i < 4; ++i) {
        int row = r0 + i;
        if (row < N) {
            float dv = rsqrtf((float)(rp[i + 1] - rp[i]) + 1.0f);
#pragma unroll
            for (int ct = 0; ct < 4; ++ct)
                gbh[(size_t)row * 64 + ct * 16 + cidx] = (__bf16)(acc[ct][i] * dv);
        }
    }
}

// =============== fused: h = relu(dinv*agg(g) + b); out = bf16((h @ W) * dinv) ===============

__global__ __launch_bounds__(256) void fused_layer_kernel(const ushort4* __restrict__ gb,
                                                          const int* __restrict__ rowptr,
                                                          const int* __restrict__ csr,
                                                          const float* __restrict__ bias,
                                                          const float* __restrict__ W,
                                                          ushort4* __restrict__ out, int N) {
    __shared__ float Ws[64 * 64];    // 16 KB
    __shared__ float T[16][72];
    {
        const float4* Wv = (const float4*)W;
        float4* Wsv = (float4*)Ws;
        for (int i = threadIdx.x; i < 64 * 16; i += 256) Wsv[i] = Wv[i];
    }
    int row = threadIdx.x >> 4;
    int node = blockIdx.x * 16 + row;
    int t = threadIdx.x & 15;
    int c = t * 4;
    float dinv = 0.f;
    if (node < N) {
        int beg = rowptr[node], end = rowptr[node + 1];
        dinv = rsqrtf((float)(end - beg) + 1.0f);
        float4 acc = bf4(gb[(size_t)node * 16 + t]);   // self-loop
        int j = beg;
        for (; j + 8 <= end; j += 8) {
            int s0 = csr[j], s1 = csr[j + 1], s2 = csr[j + 2], s3 = csr[j + 3];
            int s4 = csr[j + 4], s5 = csr[j + 5], s6 = csr[j + 6], s7 = csr[j + 7];
            float4 v0 = bf4(gb[(size_t)s0 * 16 + t]);
            float4 v1 = bf4(gb[(size_t)s1 * 16 + t]);
            float4 v2 = bf4(gb[(size_t)s2 * 16 + t]);
            float4 v3 = bf4(gb[(size_t)s3 * 16 + t]);
            float4 v4 = bf4(gb[(size_t)s4 * 16 + t]);
            float4 v5 = bf4(gb[(size_t)s5 * 16 + t]);
            float4 v6 = bf4(gb[(size_t)s6 * 16 + t]);
            float4 v7 = bf4(gb[(size_t)s7 * 16 + t]);
            acc.x += ((v0.x + v1.x) + (v2.x + v3.x)) + ((v4.x + v5.x) + (v6.x + v7.x));
            acc.y += ((v0.y + v1.y) + (v2.y + v3.y)) + ((v4.y + v5.y) + (v6.y + v7.y));
            acc.z += ((v0.z + v1.z) + (v2.z + v3.z)) + ((v4.z + v5.z) + (v6.z + v7.z));
            acc.w += ((v0.w + v1.w) + (v2.w + v3.w)) + ((v4.w + v5.w) + (v6.w + v7.w));
        }
        for (; j + 2 <= end; j += 2) {
            int s0 = csr[j], s1 = csr[j + 1];
            float4 v0 = bf4(gb[(size_t)s0 * 16 + t]);
            float4 v1 = bf4(gb[(size_t)s1 * 16 + t]);
            acc.x += v0.x + v1.x; acc.y += v0.y + v1.y;
            acc.z += v0.z + v1.z; acc.w += v0.w + v1.w;
        }
        if (j < end) {
            int s0 = csr[j];
            float4 v0 = bf4(gb[(size_t)s0 * 16 + t]);
            acc.x += v0.x; acc.y += v0.y; acc.z += v0.z; acc.w += v0.w;
        }
        float4 bb = *(const float4*)&bias[c];
        T[row][c + 0] = fmaxf(acc.x * dinv + bb.x, 0.f);
        T[row][c + 1] = fmaxf(acc.y * dinv + bb.y, 0.f);
        T[row][c + 2] = fmaxf(acc.z * dinv + bb.z, 0.f);
        T[row][c + 3] = fmaxf(acc.w * dinv + bb.w, 0.f);
    }
    __syncthreads();
    if (node >= N) return;
    float4 o = make_float4(0.f, 0.f, 0.f, 0.f);
#pragma unroll 16
    for (int k = 0; k < 64; ++k) {
        float tv = T[row][k];
        float4 wv = *(const float4*)&Ws[k * 64 + c];
        o.x += tv * wv.x; o.y += tv * wv.y;
        o.z += tv * wv.z; o.w += tv * wv.w;
    }
    out[(size_t)node * 16 + t] = pack4(o.x * dinv, o.y * dinv, o.z * dinv, o.w * dinv);
}

// =============== K4: h3 = dinv*agg(g3) + b3;  s_node = h3 . Wl ===============

__global__ __launch_bounds__(256) void agg_dot_kernel(const ushort4* __restrict__ gb,
                                                      const int* __restrict__ rowptr,
                                                      const int* __restrict__ csr,
                                                      const float* __restrict__ bias,
                                                      const float* __restrict__ Wl,
                                                      float* __restrict__ s_node, int N) {
    int tid = blockIdx.x * blockDim.x + threadIdx.x;
    int node = tid >> 4;
    if (node >= N) return;
    int t = tid & 15;
    int beg = rowptr[node], end = rowptr[node + 1];
    float dinv = rsqrtf((float)(end - beg) + 1.0f);
    float4 acc = bf4(gb[(size_t)node * 16 + t]);
    int j = beg;
    for (; j + 8 <= end; j += 8) {
        int s0 = csr[j], s1 = csr[j + 1], s2 = csr[j + 2], s3 = csr[j + 3];
        int s4 = csr[j + 4], s5 = csr[j + 5], s6 = csr[j + 6], s7 = csr[j + 7];
        float4 v0 = bf4(gb[(size_t)s0 * 16 + t]);
        float4 v1 = bf4(gb[(size_t)s1 * 16 + t]);
        float4 v2 = bf4(gb[(size_t)s2 * 16 + t]);
        float4 v3 = bf4(gb[(size_t)s3 * 16 + t]);
        float4 v4 = bf4(gb[(size_t)s4 * 16 + t]);
        float4 v5 = bf4(gb[(size_t)s5 * 16 + t]);
        float4 v6 = bf4(gb[(size_t)s6 * 16 + t]);
        float4 v7 = bf4(gb[(size_t)s7 * 16 + t]);
        acc.x += ((v0.x + v1.x) + (v2.x + v3.x)) + ((v4.x + v5.x) + (v6.x + v7.x));
        acc.y += ((v0.y + v1.y) + (v2.y + v3.y)) + ((v4.y + v5.y) + (v6.y + v7.y));
        acc.z += ((v0.z + v1.z) + (v2.z + v3.z)) + ((v4.z + v5.z) + (v6.z + v7.z));
        acc.w += ((v0.w + v1.w) + (v2.w + v3.w)) + ((v4.w + v5.w) + (v6.w + v7.w));
    }
    for (; j + 2 <= end; j += 2) {
        int s0 = csr[j], s1 = csr[j + 1];
        float4 v0 = bf4(gb[(size_t)s0 * 16 + t]);
        float4 v1 = bf4(gb[(size_t)s1 * 16 + t]);
        acc.x += v0.x + v1.x; acc.y += v0.y + v1.y;
        acc.z += v0.z + v1.z; acc.w += v0.w + v1.w;
    }
    if (j < end) {
        int s0 = csr[j];
        float4 v0 = bf4(gb[(size_t)s0 * 16 + t]);
        acc.x += v0.x; acc.y += v0.y; acc.z += v0.z; acc.w += v0.w;
    }
    float4 bb = *(const float4*)&bias[t * 4];
    float4 wl = *(const float4*)&Wl[t * 4];
    float s = (acc.x * dinv + bb.x) * wl.x + (acc.y * dinv + bb.y) * wl.y +
              (acc.z * dinv + bb.z) * wl.z + (acc.w * dinv + bb.w) * wl.w;
    s += __shfl_xor(s, 1);
    s += __shfl_xor(s, 2);
    s += __shfl_xor(s, 4);
    s += __shfl_xor(s, 8);
    if (t == 0) s_node[node] = s;
}

// =============== K5: per-graph mean over sorted batch + bl ===============

__device__ __forceinline__ int lower_bound_dev(const int* __restrict__ a, int n, int v) {
    int lo = 0, hi = n;
    while (lo < hi) { int mid = (lo + hi) >> 1; if (a[mid] < v) lo = mid + 1; else hi = mid; }
    return lo;
}

__global__ void pool_out_kernel(const float* __restrict__ s_node, const int* __restrict__ batch,
                                const float* __restrict__ bl, float* __restrict__ out, int N) {
    int gidx = blockIdx.x;
    int lo = lower_bound_dev(batch, N, gidx);
    int hi = lower_bound_dev(batch, N, gidx + 1);
    float s = 0.f;
    for (int i = lo + threadIdx.x; i < hi; i += 64) s += s_node[i];
    for (int d = 32; d; d >>= 1) s += __shfl_down(s, d);
    if (threadIdx.x == 0) out[gidx] = s / fmaxf((float)(hi - lo), 1.0f) + bl[0];
}

// =============== launcher ===============

extern "C" void kernel_launch(void* const* d_in, const int* in_sizes, int n_in,
                              void* d_out, int out_size, void* d_ws, size_t ws_size,
                              hipStream_t stream) {
    const float* x   = (const float*)d_in[0];
    const int*   ei  = (const int*)d_in[1];
    const int*   bat = (const int*)d_in[2];
    const float* W1  = (const float*)d_in[3];
    const float* b1  = (const float*)d_in[4];
    const float* W2  = (const float*)d_in[5];
    const float* b2  = (const float*)d_in[6];
    const float* W3  = (const float*)d_in[7];
    const float* b3  = (const float*)d_in[8];
    const float* Wl  = (const float*)d_in[9];
    const float* bl  = (const float*)d_in[10];

    const int N = in_sizes[0] / 128;   // 100000
    const int E = in_sizes[1] / 2;     // 1600000
    const int G = out_size;            // 1000

    const int* src = ei;
    const int* dst = ei + E;

    const int NBK = (N + BKT - 1) / BKT;       // coarse buckets (98)
    const int Np = (N + 4) & ~3;

    // workspace layout
    int*     rowptr = (int*)d_ws;                  // Np
    int*     coarse = rowptr + Np;                 // 128
    int*     bbase  = coarse + 128;                // 132 (NBK+1, padded)
    int*     gbcur  = bbase + 132;                 // NBK*16 padded cursors
    int*     csr    = gbcur + (size_t)NBK * 16;    // E
    int2*    pairs  = (int2*)(csr + E);            // E
    ushort4* gbA    = (ushort4*)(pairs + E);       // N*16 (bf16 features)
    ushort4* gbB    = gbA + (size_t)N * 16;        // N*16
    float*   s_node = (float*)(gbB + (size_t)N * 16);  // N

    // ---- CSR build ----
    hipMemsetAsync(coarse, 0, (260 + (size_t)NBK * 16) * sizeof(int), stream);
    coarse_hist<<<256, 256, 0, stream>>>(dst, coarse, E, NBK);
    coarse_scan<<<1, 64, 0, stream>>>(coarse, bbase, NBK, E);
    partition_kernel<<<(E + EPB - 1) / EPB, 256, 0, stream>>>(src, dst, bbase, gbcur, pairs, E, NBK);
    bucket_build<<<NBK, 256, 0, stream>>>(pairs, bbase, rowptr, csr, N, E);

    const int tileGrid = (N + 15) / 16;
    const int aggGrid  = (int)(((size_t)N * 16 + 255) / 256);

    gemm1_mfma<<<(N + 63) / 64, 256, 0, stream>>>(x, W1, rowptr, (__bf16*)gbA, N);
    fused_layer_kernel<<<tileGrid, 256, 0, stream>>>(gbA, rowptr, csr, b1, W2, gbB, N);
    fused_layer_kernel<<<tileGrid, 256, 0, stream>>>(gbB, rowptr, csr, b2, W3, gbA, N);
    agg_dot_kernel<<<aggGrid, 256, 0, stream>>>(gbA, rowptr, csr, b3, Wl, s_node, N);
    pool_out_kernel<<<G, 64, 0, stream>>>(s_node, bat, bl, (float*)d_out, N);
}

// Round 12
// 245.358 us; speedup vs baseline: 2.8325x; 1.1421x over previous
//
#include <hip/hip_runtime.h>
#include <stdint.h>

#define BKT 1024   // nodes per coarse bucket
#define EPB 4096   // edges per partition block

typedef __attribute__((ext_vector_type(8))) __bf16 bf16x8;
typedef __attribute__((ext_vector_type(4))) float floatx4;

// ---- bf16 helpers (RNE pack, exact expand) ----
__device__ __forceinline__ float bf2f(unsigned short h) {
    return __uint_as_float(((unsigned)h) << 16);
}
__device__ __forceinline__ float4 bf4(ushort4 v) {
    return make_float4(bf2f(v.x), bf2f(v.y), bf2f(v.z), bf2f(v.w));
}
__device__ __forceinline__ unsigned short f2bf(float f) {
    unsigned u = __float_as_uint(f);
    u = u + 0x7FFFu + ((u >> 16) & 1u);
    return (unsigned short)(u >> 16);
}
__device__ __forceinline__ ushort4 pack4(float a, float b, float c, float d) {
    ushort4 r; r.x = f2bf(a); r.y = f2bf(b); r.z = f2bf(c); r.w = f2bf(d); return r;
}

// =============== coarse (98-bin) histogram: LDS-reduced ===============

__global__ __launch_bounds__(256) void coarse_hist(const int* __restrict__ dst,
                                                   int* __restrict__ coarse, int E, int NBK) {
    __shared__ int h[128];
    if (threadIdx.x < 128) h[threadIdx.x] = 0;
    __syncthreads();
    int stride = gridDim.x * 256;
    for (int i = blockIdx.x * 256 + threadIdx.x; i < E; i += stride)
        atomicAdd(&h[dst[i] >> 10], 1);
    __syncthreads();
    if (threadIdx.x < NBK) {
        int v = h[threadIdx.x];
        if (v) atomicAdd(&coarse[threadIdx.x], v);
    }
}

__global__ void coarse_scan(const int* __restrict__ coarse, int* __restrict__ bbase,
                            int NBK, int E) {
    if (threadIdx.x == 0 && blockIdx.x == 0) {
        int run = 0;
        for (int i = 0; i < NBK; ++i) { bbase[i] = run; run += coarse[i]; }
        bbase[NBK] = E;
    }
}

// =============== Phase A: LDS-staged counting-sort partition by dst>>10 ===============

__global__ __launch_bounds__(256) void partition_kernel(const int* __restrict__ src,
                                                        const int* __restrict__ dst,
                                                        const int* __restrict__ bbase,
                                                        int* __restrict__ gbcur,
                                                        int2* __restrict__ pairs,
                                                        int E, int NBK) {
    __shared__ int2 stage[EPB];          // 32 KB
    __shared__ int  hist[128], offs[129], gbase[128], lcur[128];
    int base = blockIdx.x * EPB;
    int cntE = min(EPB, E - base);
    if (threadIdx.x < 128) hist[threadIdx.x] = 0;
    __syncthreads();
    for (int i = threadIdx.x; i < cntE; i += 256) {
        int b = dst[base + i] >> 10;
        atomicAdd(&hist[b], 1);
    }
    __syncthreads();
    if (threadIdx.x == 0) {
        int run = 0;
        for (int b = 0; b < NBK; ++b) { offs[b] = run; run += hist[b]; }
        offs[NBK] = run;
    }
    __syncthreads();
    if (threadIdx.x < NBK) {
        int b = threadIdx.x;
        int h = hist[b];
        if (h > 0) gbase[b] = bbase[b] + atomicAdd(&gbcur[b << 4], h);
        lcur[b] = offs[b];
    }
    __syncthreads();
    for (int i = threadIdx.x; i < cntE; i += 256) {
        int e = base + i;
        int d = dst[e];
        int b = d >> 10;
        int slot = atomicAdd(&lcur[b], 1);
        stage[slot] = make_int2(src[e], d);
    }
    __syncthreads();
    int total = offs[NBK];
    for (int j = threadIdx.x; j < total; j += 256) {
        int lo = 0, hi = NBK;
        while (lo < hi) { int mid = (lo + hi) >> 1; if (offs[mid + 1] <= j) lo = mid + 1; else hi = mid; }
        pairs[gbase[lo] + (j - offs[lo])] = stage[j];
    }
}

// =============== Phase B: per-bucket hist + scan -> rowptr, then scatter -> csr ===============

__global__ __launch_bounds__(256) void bucket_build(const int2* __restrict__ pairs,
                                                    const int* __restrict__ bbase,
                                                    int* __restrict__ rowptr,
                                                    int* __restrict__ csr, int N, int E) {
    __shared__ int cnt[BKT];      // counters -> cursors
    __shared__ int psum[256];
    int b = blockIdx.x;
    int nbase = b << 10;
    int pbeg = bbase[b], pend = bbase[b + 1];
    for (int i = threadIdx.x; i < BKT; i += 256) cnt[i] = 0;
    __syncthreads();
    for (int j = pbeg + (int)threadIdx.x; j < pend; j += 256)
        atomicAdd(&cnt[pairs[j].y - nbase], 1);
    __syncthreads();
    int i0 = threadIdx.x * 4;
    int c0 = cnt[i0], c1 = cnt[i0 + 1], c2 = cnt[i0 + 2], c3 = cnt[i0 + 3];
    int local = c0 + c1 + c2 + c3;
    psum[threadIdx.x] = local;
    __syncthreads();
    for (int d = 1; d < 256; d <<= 1) {
        int t = (threadIdx.x >= d) ? psum[threadIdx.x - d] : 0;
        __syncthreads();
        psum[threadIdx.x] += t;
        __syncthreads();
    }
    int excl = psum[threadIdx.x] - local;
    int o0 = pbeg + excl;
    int o1 = o0 + c0, o2 = o1 + c1, o3 = o2 + c2;
    int n0 = nbase + i0;
    if (n0 < N)     rowptr[n0]     = o0;
    if (n0 + 1 < N) rowptr[n0 + 1] = o1;
    if (n0 + 2 < N) rowptr[n0 + 2] = o2;
    if (n0 + 3 < N) rowptr[n0 + 3] = o3;
    cnt[i0] = o0; cnt[i0 + 1] = o1; cnt[i0 + 2] = o2; cnt[i0 + 3] = o3;
    __syncthreads();
    for (int j = pbeg + (int)threadIdx.x; j < pend; j += 256) {
        int2 p = pairs[j];
        int slot = atomicAdd(&cnt[p.y - nbase], 1);
        csr[slot] = p.x;
    }
    if (b == 0 && threadIdx.x == 0) rowptr[N] = E;
}

// =============== K1 (MFMA): g1 = bf16( (X[N,128] @ W1[128,64]) * dinv ) ===============

__global__ __launch_bounds__(256) void gemm1_mfma(const float* __restrict__ X,
                                                  const float* __restrict__ W,
                                                  const int* __restrict__ rowptr,
                                                  __bf16* __restrict__ gbh, int N) {
    __shared__ __align__(16) __bf16 Wt[64][136];
    for (int i = threadIdx.x; i < 128 * 64; i += 256) {
        int k = i >> 6, c = i & 63;
        Wt[c][k] = (__bf16)W[i];
    }
    __syncthreads();

    int wave = threadIdx.x >> 6;
    int l = threadIdx.x & 63;
    int cidx = l & 15;
    int g = l >> 4;
    int wbase = blockIdx.x * 64 + wave * 16;

    int arow = wbase + cidx;
    int arowc = min(arow, N - 1);
    const float4* xr = (const float4*)(X + (size_t)arowc * 128);
    bf16x8 afr[4];
#pragma unroll
    for (int kb = 0; kb < 4; ++kb) {
        float4 p = xr[kb * 8 + g * 2];
        float4 q = xr[kb * 8 + g * 2 + 1];
        bf16x8 a;
        a[0] = (__bf16)p.x; a[1] = (__bf16)p.y; a[2] = (__bf16)p.z; a[3] = (__bf16)p.w;
        a[4] = (__bf16)q.x; a[5] = (__bf16)q.y; a[6] = (__bf16)q.z; a[7] = (__bf16)q.w;
        afr[kb] = a;
    }

    floatx4 acc[4];
#pragma unroll
    for (int ct = 0; ct < 4; ++ct) acc[ct] = (floatx4){0.f, 0.f, 0.f, 0.f};

#pragma unroll
    for (int ct = 0; ct < 4; ++ct) {
#pragma unroll
        for (int kb = 0; kb < 4; ++kb) {
            bf16x8 bfr = *(const bf16x8*)&Wt[ct * 16 + cidx][kb * 32 + g * 8];
            acc[ct] = __builtin_amdgcn_mfma_f32_16x16x32_bf16(afr[kb], bfr, acc[ct], 0, 0, 0);
        }
    }

    int r0 = wbase + g * 4;
    int rp[5];
#pragma unroll
    for (int i = 0; i < 5; ++i) rp[i] = rowptr[min(r0 + i, N)];
#pragma unroll
    for (int i = 0; i < 4; ++i) {
        int row = r0 + i;
        if (row < N) {
            float dv = rsqrtf((float)(rp[i + 1] - rp[i]) + 1.0f);
#pragma unroll
            for (int ct = 0; ct < 4; ++ct)
                gbh[(size_t)row * 64 + ct * 16 + cidx] = (__bf16)(acc[ct][i] * dv);
        }
    }
}

// =============== fused: h = relu(dinv*agg(g) + b); out = (h @ W) * dinv ===============
// WRITE_P=false: store bf16 rows. WRITE_P=true: store only p[node] = out_row . Wl (fp32).

template <bool WRITE_P>
__global__ __launch_bounds__(256) void fused_layer_kernel(const ushort4* __restrict__ gb,
                                                          const int* __restrict__ rowptr,
                                                          const int* __restrict__ csr,
                                                          const float* __restrict__ bias,
                                                          const float* __restrict__ W,
                                                          ushort4* __restrict__ out,
                                                          const float* __restrict__ Wl,
                                                          float* __restrict__ p, int N) {
    __shared__ float Ws[64 * 64];    // 16 KB
    __shared__ float T[16][72];
    {
        const float4* Wv = (const float4*)W;
        float4* Wsv = (float4*)Ws;
        for (int i = threadIdx.x; i < 64 * 16; i += 256) Wsv[i] = Wv[i];
    }
    int row = threadIdx.x >> 4;
    int node = blockIdx.x * 16 + row;
    int t = threadIdx.x & 15;
    int c = t * 4;
    float dinv = 0.f;
    if (node < N) {
        int beg = rowptr[node], end = rowptr[node + 1];
        dinv = rsqrtf((float)(end - beg) + 1.0f);
        float4 acc = bf4(gb[(size_t)node * 16 + t]);   // self-loop
        int j = beg;
        for (; j + 8 <= end; j += 8) {
            int s0 = csr[j], s1 = csr[j + 1], s2 = csr[j + 2], s3 = csr[j + 3];
            int s4 = csr[j + 4], s5 = csr[j + 5], s6 = csr[j + 6], s7 = csr[j + 7];
            float4 v0 = bf4(gb[(size_t)s0 * 16 + t]);
            float4 v1 = bf4(gb[(size_t)s1 * 16 + t]);
            float4 v2 = bf4(gb[(size_t)s2 * 16 + t]);
            float4 v3 = bf4(gb[(size_t)s3 * 16 + t]);
            float4 v4 = bf4(gb[(size_t)s4 * 16 + t]);
            float4 v5 = bf4(gb[(size_t)s5 * 16 + t]);
            float4 v6 = bf4(gb[(size_t)s6 * 16 + t]);
            float4 v7 = bf4(gb[(size_t)s7 * 16 + t]);
            acc.x += ((v0.x + v1.x) + (v2.x + v3.x)) + ((v4.x + v5.x) + (v6.x + v7.x));
            acc.y += ((v0.y + v1.y) + (v2.y + v3.y)) + ((v4.y + v5.y) + (v6.y + v7.y));
            acc.z += ((v0.z + v1.z) + (v2.z + v3.z)) + ((v4.z + v5.z) + (v6.z + v7.z));
            acc.w += ((v0.w + v1.w) + (v2.w + v3.w)) + ((v4.w + v5.w) + (v6.w + v7.w));
        }
        for (; j + 2 <= end; j += 2) {
            int s0 = csr[j], s1 = csr[j + 1];
            float4 v0 = bf4(gb[(size_t)s0 * 16 + t]);
            float4 v1 = bf4(gb[(size_t)s1 * 16 + t]);
            acc.x += v0.x + v1.x; acc.y += v0.y + v1.y;
            acc.z += v0.z + v1.z; acc.w += v0.w + v1.w;
        }
        if (j < end) {
            int s0 = csr[j];
            float4 v0 = bf4(gb[(size_t)s0 * 16 + t]);
            acc.x += v0.x; acc.y += v0.y; acc.z += v0.z; acc.w += v0.w;
        }
        float4 bb = *(const float4*)&bias[c];
        T[row][c + 0] = fmaxf(acc.x * dinv + bb.x, 0.f);
        T[row][c + 1] = fmaxf(acc.y * dinv + bb.y, 0.f);
        T[row][c + 2] = fmaxf(acc.z * dinv + bb.z, 0.f);
        T[row][c + 3] = fmaxf(acc.w * dinv + bb.w, 0.f);
    }
    __syncthreads();
    if (node >= N) return;
    float4 o = make_float4(0.f, 0.f, 0.f, 0.f);
#pragma unroll 16
    for (int k = 0; k < 64; ++k) {
        float tv = T[row][k];
        float4 wv = *(const float4*)&Ws[k * 64 + c];
        o.x += tv * wv.x; o.y += tv * wv.y;
        o.z += tv * wv.z; o.w += tv * wv.w;
    }
    if (WRITE_P) {
        // p[node] = (o * dinv) . Wl   (fp32, pre-bf16-rounding)
        float4 wl = *(const float4*)&Wl[c];
        float s = (o.x * wl.x + o.y * wl.y) + (o.z * wl.z + o.w * wl.w);
        s += __shfl_xor(s, 1);
        s += __shfl_xor(s, 2);
        s += __shfl_xor(s, 4);
        s += __shfl_xor(s, 8);
        if (t == 0) p[node] = s * dinv;
    } else {
        out[(size_t)node * 16 + t] = pack4(o.x * dinv, o.y * dinv, o.z * dinv, o.w * dinv);
    }
}

// =============== scalar aggregation: s_node[n] = dinv_n * (p[n] + sum p[csr]) ===============

__global__ __launch_bounds__(256) void scalar_agg(const float* __restrict__ p,
                                                  const int* __restrict__ rowptr,
                                                  const int* __restrict__ csr,
                                                  float* __restrict__ s_node, int N) {
    int n = blockIdx.x * 256 + threadIdx.x;
    if (n >= N) return;
    int beg = rowptr[n], end = rowptr[n + 1];
    float dinv = rsqrtf((float)(end - beg) + 1.0f);
    float acc = p[n];
    int j = beg;
    for (; j + 4 <= end; j += 4) {
        float a0 = p[csr[j]], a1 = p[csr[j + 1]], a2 = p[csr[j + 2]], a3 = p[csr[j + 3]];
        acc += (a0 + a1) + (a2 + a3);
    }
    for (; j < end; ++j) acc += p[csr[j]];
    s_node[n] = acc * dinv;
}

// =============== K5: per-graph mean over sorted batch + (b3.Wl) + bl ===============

__device__ __forceinline__ int lower_bound_dev(const int* __restrict__ a, int n, int v) {
    int lo = 0, hi = n;
    while (lo < hi) { int mid = (lo + hi) >> 1; if (a[mid] < v) lo = mid + 1; else hi = mid; }
    return lo;
}

__global__ void pool_out_kernel(const float* __restrict__ s_node, const int* __restrict__ batch,
                                const float* __restrict__ b3, const float* __restrict__ Wl,
                                const float* __restrict__ bl, float* __restrict__ out, int N) {
    // bldot = b3 . Wl (single wave, 64 lanes)
    float v = b3[threadIdx.x] * Wl[threadIdx.x];
    for (int d = 32; d; d >>= 1) v += __shfl_down(v, d);
    float bldot = __shfl(v, 0, 64);

    int gidx = blockIdx.x;
    int lo = lower_bound_dev(batch, N, gidx);
    int hi = lower_bound_dev(batch, N, gidx + 1);
    float s = 0.f;
    for (int i = lo + threadIdx.x; i < hi; i += 64) s += s_node[i];
    for (int d = 32; d; d >>= 1) s += __shfl_down(s, d);
    if (threadIdx.x == 0)
        out[gidx] = s / fmaxf((float)(hi - lo), 1.0f) + bldot + bl[0];
}

// =============== launcher ===============

extern "C" void kernel_launch(void* const* d_in, const int* in_sizes, int n_in,
                              void* d_out, int out_size, void* d_ws, size_t ws_size,
                              hipStream_t stream) {
    const float* x   = (const float*)d_in[0];
    const int*   ei  = (const int*)d_in[1];
    const int*   bat = (const int*)d_in[2];
    const float* W1  = (const float*)d_in[3];
    const float* b1  = (const float*)d_in[4];
    const float* W2  = (const float*)d_in[5];
    const float* b2  = (const float*)d_in[6];
    const float* W3  = (const float*)d_in[7];
    const float* b3  = (const float*)d_in[8];
    const float* Wl  = (const float*)d_in[9];
    const float* bl  = (const float*)d_in[10];

    const int N = in_sizes[0] / 128;   // 100000
    const int E = in_sizes[1] / 2;     // 1600000
    const int G = out_size;            // 1000

    const int* src = ei;
    const int* dst = ei + E;

    const int NBK = (N + BKT - 1) / BKT;       // coarse buckets (98)
    const int Np = (N + 4) & ~3;

    // workspace layout
    int*     rowptr = (int*)d_ws;                  // Np
    int*     coarse = rowptr + Np;                 // 128
    int*     bbase  = coarse + 128;                // 132 (NBK+1, padded)
    int*     gbcur  = bbase + 132;                 // NBK*16 padded cursors
    int*     csr    = gbcur + (size_t)NBK * 16;    // E
    int2*    pairs  = (int2*)(csr + E);            // E
    ushort4* gbA    = (ushort4*)(pairs + E);       // N*16 (bf16 features)
    ushort4* gbB    = gbA + (size_t)N * 16;        // N*16
    float*   pbuf   = (float*)(gbB + (size_t)N * 16);  // N
    float*   s_node = pbuf + N;                        // N

    // ---- CSR build ----
    hipMemsetAsync(coarse, 0, (260 + (size_t)NBK * 16) * sizeof(int), stream);
    coarse_hist<<<256, 256, 0, stream>>>(dst, coarse, E, NBK);
    coarse_scan<<<1, 64, 0, stream>>>(coarse, bbase, NBK, E);
    partition_kernel<<<(E + EPB - 1) / EPB, 256, 0, stream>>>(src, dst, bbase, gbcur, pairs, E, NBK);
    bucket_build<<<NBK, 256, 0, stream>>>(pairs, bbase, rowptr, csr, N, E);

    const int tileGrid = (N + 15) / 16;

    gemm1_mfma<<<(N + 63) / 64, 256, 0, stream>>>(x, W1, rowptr, (__bf16*)gbA, N);
    fused_layer_kernel<false><<<tileGrid, 256, 0, stream>>>(gbA, rowptr, csr, b1, W2, gbB, nullptr, nullptr, N);
    fused_layer_kernel<true><<<tileGrid, 256, 0, stream>>>(gbB, rowptr, csr, b2, W3, nullptr, Wl, pbuf, N);
    scalar_agg<<<(N + 255) / 256, 256, 0, stream>>>(pbuf, rowptr, csr, s_node, N);
    pool_out_kernel<<<G, 64, 0, stream>>>(s_node, bat, b3, Wl, bl, (float*)d_out, N);
}

// Round 13
// 232.670 us; speedup vs baseline: 2.9870x; 1.0545x over previous
//
#include <hip/hip_runtime.h>
#include <stdint.h>

#define BKT 1024   // nodes per coarse bucket
#define EPB 4096   // edges per partition block

typedef __attribute__((ext_vector_type(8))) __bf16 bf16x8;
typedef __attribute__((ext_vector_type(4))) float floatx4;

// ---- bf16 helpers (RNE pack, exact expand) ----
__device__ __forceinline__ float bf2f(unsigned short h) {
    return __uint_as_float(((unsigned)h) << 16);
}
__device__ __forceinline__ float4 bf4(ushort4 v) {
    return make_float4(bf2f(v.x), bf2f(v.y), bf2f(v.z), bf2f(v.w));
}
__device__ __forceinline__ unsigned short f2bf(float f) {
    unsigned u = __float_as_uint(f);
    u = u + 0x7FFFu + ((u >> 16) & 1u);
    return (unsigned short)(u >> 16);
}
__device__ __forceinline__ ushort4 pack4(float a, float b, float c, float d) {
    ushort4 r; r.x = f2bf(a); r.y = f2bf(b); r.z = f2bf(c); r.w = f2bf(d); return r;
}

// =============== w3l = W3 . Wl (64-vector) ===============

__global__ void w3l_kernel(const float* __restrict__ W3, const float* __restrict__ Wl,
                           float* __restrict__ w3l) {
    int k = threadIdx.x;   // 64 threads
    float s = 0.f;
#pragma unroll 16
    for (int c = 0; c < 64; ++c) s += W3[k * 64 + c] * Wl[c];
    w3l[k] = s;
}

// =============== coarse (98-bin) histogram: LDS-reduced, int4 loads ===============

__global__ __launch_bounds__(256) void coarse_hist(const int* __restrict__ dst,
                                                   int* __restrict__ coarse, int E, int NBK) {
    __shared__ int h[128];
    if (threadIdx.x < 128) h[threadIdx.x] = 0;
    __syncthreads();
    int stride = gridDim.x * 256;
    int gid = blockIdx.x * 256 + threadIdx.x;
    const int4* d4 = (const int4*)dst;
    int E4 = E >> 2;
    for (int i = gid; i < E4; i += stride) {
        int4 v = d4[i];
        atomicAdd(&h[v.x >> 10], 1);
        atomicAdd(&h[v.y >> 10], 1);
        atomicAdd(&h[v.z >> 10], 1);
        atomicAdd(&h[v.w >> 10], 1);
    }
    for (int i = (E4 << 2) + gid; i < E; i += stride)
        atomicAdd(&h[dst[i] >> 10], 1);
    __syncthreads();
    if (threadIdx.x < NBK) {
        int v = h[threadIdx.x];
        if (v) atomicAdd(&coarse[threadIdx.x], v);
    }
}

__global__ void coarse_scan(const int* __restrict__ coarse, int* __restrict__ bbase,
                            int NBK, int E) {
    if (threadIdx.x == 0 && blockIdx.x == 0) {
        int run = 0;
        for (int i = 0; i < NBK; ++i) { bbase[i] = run; run += coarse[i]; }
        bbase[NBK] = E;
    }
}

// =============== Phase A: LDS-staged counting-sort partition by dst>>10 ===============

__global__ __launch_bounds__(256) void partition_kernel(const int* __restrict__ src,
                                                        const int* __restrict__ dst,
                                                        const int* __restrict__ bbase,
                                                        int* __restrict__ gbcur,
                                                        int2* __restrict__ pairs,
                                                        int E, int NBK) {
    __shared__ int2 stage[EPB];          // 32 KB
    __shared__ int  hist[128], offs[129], gbase[128], lcur[128];
    int base = blockIdx.x * EPB;
    int cntE = min(EPB, E - base);
    if (threadIdx.x < 128) hist[threadIdx.x] = 0;
    __syncthreads();
    {
        const int4* d4 = (const int4*)(dst + base);   // base is 4096-aligned
        int c4 = cntE >> 2;
        for (int i = threadIdx.x; i < c4; i += 256) {
            int4 v = d4[i];
            atomicAdd(&hist[v.x >> 10], 1);
            atomicAdd(&hist[v.y >> 10], 1);
            atomicAdd(&hist[v.z >> 10], 1);
            atomicAdd(&hist[v.w >> 10], 1);
        }
        for (int i = (c4 << 2) + (int)threadIdx.x; i < cntE; i += 256)
            atomicAdd(&hist[dst[base + i] >> 10], 1);
    }
    __syncthreads();
    if (threadIdx.x == 0) {
        int run = 0;
        for (int b = 0; b < NBK; ++b) { offs[b] = run; run += hist[b]; }
        offs[NBK] = run;
    }
    __syncthreads();
    if (threadIdx.x < NBK) {
        int b = threadIdx.x;
        int h = hist[b];
        if (h > 0) gbase[b] = bbase[b] + atomicAdd(&gbcur[b << 4], h);
        lcur[b] = offs[b];
    }
    __syncthreads();
    for (int i = threadIdx.x; i < cntE; i += 256) {
        int e = base + i;
        int d = dst[e];
        int b = d >> 10;
        int slot = atomicAdd(&lcur[b], 1);
        stage[slot] = make_int2(src[e], d);
    }
    __syncthreads();
    int total = offs[NBK];
    for (int j = threadIdx.x; j < total; j += 256) {
        int lo = 0, hi = NBK;
        while (lo < hi) { int mid = (lo + hi) >> 1; if (offs[mid + 1] <= j) lo = mid + 1; else hi = mid; }
        pairs[gbase[lo] + (j - offs[lo])] = stage[j];
    }
}

// =============== Phase B: per-bucket hist + scan -> rowptr, then scatter -> csr ===============

__global__ __launch_bounds__(256) void bucket_build(const int2* __restrict__ pairs,
                                                    const int* __restrict__ bbase,
                                                    int* __restrict__ rowptr,
                                                    int* __restrict__ csr, int N, int E) {
    __shared__ int cnt[BKT];      // counters -> cursors
    __shared__ int psum[256];
    int b = blockIdx.x;
    int nbase = b << 10;
    int pbeg = bbase[b], pend = bbase[b + 1];
    for (int i = threadIdx.x; i < BKT; i += 256) cnt[i] = 0;
    __syncthreads();
    for (int j = pbeg + (int)threadIdx.x; j < pend; j += 256)
        atomicAdd(&cnt[pairs[j].y - nbase], 1);
    __syncthreads();
    int i0 = threadIdx.x * 4;
    int c0 = cnt[i0], c1 = cnt[i0 + 1], c2 = cnt[i0 + 2], c3 = cnt[i0 + 3];
    int local = c0 + c1 + c2 + c3;
    psum[threadIdx.x] = local;
    __syncthreads();
    for (int d = 1; d < 256; d <<= 1) {
        int t = (threadIdx.x >= d) ? psum[threadIdx.x - d] : 0;
        __syncthreads();
        psum[threadIdx.x] += t;
        __syncthreads();
    }
    int excl = psum[threadIdx.x] - local;
    int o0 = pbeg + excl;
    int o1 = o0 + c0, o2 = o1 + c1, o3 = o2 + c2;
    int n0 = nbase + i0;
    if (n0 < N)     rowptr[n0]     = o0;
    if (n0 + 1 < N) rowptr[n0 + 1] = o1;
    if (n0 + 2 < N) rowptr[n0 + 2] = o2;
    if (n0 + 3 < N) rowptr[n0 + 3] = o3;
    cnt[i0] = o0; cnt[i0 + 1] = o1; cnt[i0 + 2] = o2; cnt[i0 + 3] = o3;
    __syncthreads();
    for (int j = pbeg + (int)threadIdx.x; j < pend; j += 256) {
        int2 p = pairs[j];
        int slot = atomicAdd(&cnt[p.y - nbase], 1);
        csr[slot] = p.x;
    }
    if (b == 0 && threadIdx.x == 0) rowptr[N] = E;
}

// =============== K1 (MFMA): g1 = bf16( (X[N,128] @ W1[128,64]) * dinv ) ===============

__global__ __launch_bounds__(256) void gemm1_mfma(const float* __restrict__ X,
                                                  const float* __restrict__ W,
                                                  const int* __restrict__ rowptr,
                                                  __bf16* __restrict__ gbh, int N) {
    __shared__ __align__(16) __bf16 Wt[64][136];
    for (int i = threadIdx.x; i < 128 * 64; i += 256) {
        int k = i >> 6, c = i & 63;
        Wt[c][k] = (__bf16)W[i];
    }
    __syncthreads();

    int wave = threadIdx.x >> 6;
    int l = threadIdx.x & 63;
    int cidx = l & 15;
    int g = l >> 4;
    int wbase = blockIdx.x * 64 + wave * 16;

    int arow = wbase + cidx;
    int arowc = min(arow, N - 1);
    const float4* xr = (const float4*)(X + (size_t)arowc * 128);
    bf16x8 afr[4];
#pragma unroll
    for (int kb = 0; kb < 4; ++kb) {
        float4 p = xr[kb * 8 + g * 2];
        float4 q = xr[kb * 8 + g * 2 + 1];
        bf16x8 a;
        a[0] = (__bf16)p.x; a[1] = (__bf16)p.y; a[2] = (__bf16)p.z; a[3] = (__bf16)p.w;
        a[4] = (__bf16)q.x; a[5] = (__bf16)q.y; a[6] = (__bf16)q.z; a[7] = (__bf16)q.w;
        afr[kb] = a;
    }

    floatx4 acc[4];
#pragma unroll
    for (int ct = 0; ct < 4; ++ct) acc[ct] = (floatx4){0.f, 0.f, 0.f, 0.f};

#pragma unroll
    for (int ct = 0; ct < 4; ++ct) {
#pragma unroll
        for (int kb = 0; kb < 4; ++kb) {
            bf16x8 bfr = *(const bf16x8*)&Wt[ct * 16 + cidx][kb * 32 + g * 8];
            acc[ct] = __builtin_amdgcn_mfma_f32_16x16x32_bf16(afr[kb], bfr, acc[ct], 0, 0, 0);
        }
    }

    int r0 = wbase + g * 4;
    int rp[5];
#pragma unroll
    for (int i = 0; i < 5; ++i) rp[i] = rowptr[min(r0 + i, N)];
#pragma unroll
    for (int i = 0; i < 4; ++i) {
        int row = r0 + i;
        if (row < N) {
            float dv = rsqrtf((float)(rp[i + 1] - rp[i]) + 1.0f);
#pragma unroll
            for (int ct = 0; ct < 4; ++ct)
                gbh[(size_t)row * 64 + ct * 16 + cidx] = (__bf16)(acc[ct][i] * dv);
        }
    }
}

// =============== fused: h = relu(dinv*agg(g) + b); out = bf16((h @ W) * dinv) ===============

__global__ __launch_bounds__(256) void fused_layer_kernel(const ushort4* __restrict__ gb,
                                                          const int* __restrict__ rowptr,
                                                          const int* __restrict__ csr,
                                                          const float* __restrict__ bias,
                                                          const float* __restrict__ W,
                                                          ushort4* __restrict__ out, int N) {
    __shared__ float Ws[64 * 64];    // 16 KB
    __shared__ float T[16][72];
    {
        const float4* Wv = (const float4*)W;
        float4* Wsv = (float4*)Ws;
        for (int i = threadIdx.x; i < 64 * 16; i += 256) Wsv[i] = Wv[i];
    }
    int row = threadIdx.x >> 4;
    int node = blockIdx.x * 16 + row;
    int t = threadIdx.x & 15;
    int c = t * 4;
    float dinv = 0.f;
    if (node < N) {
        int beg = rowptr[node], end = rowptr[node + 1];
        dinv = rsqrtf((float)(end - beg) + 1.0f);
        float4 acc = bf4(gb[(size_t)node * 16 + t]);   // self-loop
        int j = beg;
        for (; j + 8 <= end; j += 8) {
            int s0 = csr[j], s1 = csr[j + 1], s2 = csr[j + 2], s3 = csr[j + 3];
            int s4 = csr[j + 4], s5 = csr[j + 5], s6 = csr[j + 6], s7 = csr[j + 7];
            float4 v0 = bf4(gb[(size_t)s0 * 16 + t]);
            float4 v1 = bf4(gb[(size_t)s1 * 16 + t]);
            float4 v2 = bf4(gb[(size_t)s2 * 16 + t]);
            float4 v3 = bf4(gb[(size_t)s3 * 16 + t]);
            float4 v4 = bf4(gb[(size_t)s4 * 16 + t]);
            float4 v5 = bf4(gb[(size_t)s5 * 16 + t]);
            float4 v6 = bf4(gb[(size_t)s6 * 16 + t]);
            float4 v7 = bf4(gb[(size_t)s7 * 16 + t]);
            acc.x += ((v0.x + v1.x) + (v2.x + v3.x)) + ((v4.x + v5.x) + (v6.x + v7.x));
            acc.y += ((v0.y + v1.y) + (v2.y + v3.y)) + ((v4.y + v5.y) + (v6.y + v7.y));
            acc.z += ((v0.z + v1.z) + (v2.z + v3.z)) + ((v4.z + v5.z) + (v6.z + v7.z));
            acc.w += ((v0.w + v1.w) + (v2.w + v3.w)) + ((v4.w + v5.w) + (v6.w + v7.w));
        }
        for (; j + 2 <= end; j += 2) {
            int s0 = csr[j], s1 = csr[j + 1];
            float4 v0 = bf4(gb[(size_t)s0 * 16 + t]);
            float4 v1 = bf4(gb[(size_t)s1 * 16 + t]);
            acc.x += v0.x + v1.x; acc.y += v0.y + v1.y;
            acc.z += v0.z + v1.z; acc.w += v0.w + v1.w;
        }
        if (j < end) {
            int s0 = csr[j];
            float4 v0 = bf4(gb[(size_t)s0 * 16 + t]);
            acc.x += v0.x; acc.y += v0.y; acc.z += v0.z; acc.w += v0.w;
        }
        float4 bb = *(const float4*)&bias[c];
        T[row][c + 0] = fmaxf(acc.x * dinv + bb.x, 0.f);
        T[row][c + 1] = fmaxf(acc.y * dinv + bb.y, 0.f);
        T[row][c + 2] = fmaxf(acc.z * dinv + bb.z, 0.f);
        T[row][c + 3] = fmaxf(acc.w * dinv + bb.w, 0.f);
    }
    __syncthreads();
    if (node >= N) return;
    float4 o = make_float4(0.f, 0.f, 0.f, 0.f);
#pragma unroll 16
    for (int k = 0; k < 64; ++k) {
        float tv = T[row][k];
        float4 wv = *(const float4*)&Ws[k * 64 + c];
        o.x += tv * wv.x; o.y += tv * wv.y;
        o.z += tv * wv.z; o.w += tv * wv.w;
    }
    out[(size_t)node * 16 + t] = pack4(o.x * dinv, o.y * dinv, o.z * dinv, o.w * dinv);
}

// =============== K3: p[n] = dinv * ( relu(dinv*agg(g2)+b2) . w3l ) ===============
// w3l = W3.Wl commutes layer-3's GEMM out of existence. Zero LDS -> full occupancy.

__global__ __launch_bounds__(256) void agg_dot2_kernel(const ushort4* __restrict__ gb,
                                                       const int* __restrict__ rowptr,
                                                       const int* __restrict__ csr,
                                                       const float* __restrict__ bias,
                                                       const float* __restrict__ w3l,
                                                       float* __restrict__ p, int N) {
    int tid = blockIdx.x * blockDim.x + threadIdx.x;
    int node = tid >> 4;
    if (node >= N) return;
    int t = tid & 15;
    int beg = rowptr[node], end = rowptr[node + 1];
    float dinv = rsqrtf((float)(end - beg) + 1.0f);
    float4 acc = bf4(gb[(size_t)node * 16 + t]);
    int j = beg;
    for (; j + 8 <= end; j += 8) {
        int s0 = csr[j], s1 = csr[j + 1], s2 = csr[j + 2], s3 = csr[j + 3];
        int s4 = csr[j + 4], s5 = csr[j + 5], s6 = csr[j + 6], s7 = csr[j + 7];
        float4 v0 = bf4(gb[(size_t)s0 * 16 + t]);
        float4 v1 = bf4(gb[(size_t)s1 * 16 + t]);
        float4 v2 = bf4(gb[(size_t)s2 * 16 + t]);
        float4 v3 = bf4(gb[(size_t)s3 * 16 + t]);
        float4 v4 = bf4(gb[(size_t)s4 * 16 + t]);
        float4 v5 = bf4(gb[(size_t)s5 * 16 + t]);
        float4 v6 = bf4(gb[(size_t)s6 * 16 + t]);
        float4 v7 = bf4(gb[(size_t)s7 * 16 + t]);
        acc.x += ((v0.x + v1.x) + (v2.x + v3.x)) + ((v4.x + v5.x) + (v6.x + v7.x));
        acc.y += ((v0.y + v1.y) + (v2.y + v3.y)) + ((v4.y + v5.y) + (v6.y + v7.y));
        acc.z += ((v0.z + v1.z) + (v2.z + v3.z)) + ((v4.z + v5.z) + (v6.z + v7.z));
        acc.w += ((v0.w + v1.w) + (v2.w + v3.w)) + ((v4.w + v5.w) + (v6.w + v7.w));
    }
    for (; j + 2 <= end; j += 2) {
        int s0 = csr[j], s1 = csr[j + 1];
        float4 v0 = bf4(gb[(size_t)s0 * 16 + t]);
        float4 v1 = bf4(gb[(size_t)s1 * 16 + t]);
        acc.x += v0.x + v1.x; acc.y += v0.y + v1.y;
        acc.z += v0.z + v1.z; acc.w += v0.w + v1.w;
    }
    if (j < end) {
        int s0 = csr[j];
        float4 v0 = bf4(gb[(size_t)s0 * 16 + t]);
        acc.x += v0.x; acc.y += v0.y; acc.z += v0.z; acc.w += v0.w;
    }
    float4 bb = *(const float4*)&bias[t * 4];
    float4 wv = *(const float4*)&w3l[t * 4];
    float hx = fmaxf(acc.x * dinv + bb.x, 0.f);
    float hy = fmaxf(acc.y * dinv + bb.y, 0.f);
    float hz = fmaxf(acc.z * dinv + bb.z, 0.f);
    float hw = fmaxf(acc.w * dinv + bb.w, 0.f);
    float s = (hx * wv.x + hy * wv.y) + (hz * wv.z + hw * wv.w);
    s += __shfl_xor(s, 1);
    s += __shfl_xor(s, 2);
    s += __shfl_xor(s, 4);
    s += __shfl_xor(s, 8);
    if (t == 0) p[node] = s * dinv;
}

// =============== scalar aggregation: s_node[n] = dinv_n * (p[n] + sum p[csr]) ===============

__global__ __launch_bounds__(256) void scalar_agg(const float* __restrict__ p,
                                                  const int* __restrict__ rowptr,
                                                  const int* __restrict__ csr,
                                                  float* __restrict__ s_node, int N) {
    int n = blockIdx.x * 256 + threadIdx.x;
    if (n >= N) return;
    int beg = rowptr[n], end = rowptr[n + 1];
    float dinv = rsqrtf((float)(end - beg) + 1.0f);
    float acc = p[n];
    int j = beg;
    for (; j + 4 <= end; j += 4) {
        float a0 = p[csr[j]], a1 = p[csr[j + 1]], a2 = p[csr[j + 2]], a3 = p[csr[j + 3]];
        acc += (a0 + a1) + (a2 + a3);
    }
    for (; j < end; ++j) acc += p[csr[j]];
    s_node[n] = acc * dinv;
}

// =============== K5: per-graph mean over sorted batch + (b3.Wl) + bl ===============

__device__ __forceinline__ int lower_bound_dev(const int* __restrict__ a, int n, int v) {
    int lo = 0, hi = n;
    while (lo < hi) { int mid = (lo + hi) >> 1; if (a[mid] < v) lo = mid + 1; else hi = mid; }
    return lo;
}

__global__ void pool_out_kernel(const float* __restrict__ s_node, const int* __restrict__ batch,
                                const float* __restrict__ b3, const float* __restrict__ Wl,
                                const float* __restrict__ bl, float* __restrict__ out, int N) {
    float v = b3[threadIdx.x] * Wl[threadIdx.x];
    for (int d = 32; d; d >>= 1) v += __shfl_down(v, d);
    float bldot = __shfl(v, 0, 64);

    int gidx = blockIdx.x;
    int lo = lower_bound_dev(batch, N, gidx);
    int hi = lower_bound_dev(batch, N, gidx + 1);
    float s = 0.f;
    for (int i = lo + threadIdx.x; i < hi; i += 64) s += s_node[i];
    for (int d = 32; d; d >>= 1) s += __shfl_down(s, d);
    if (threadIdx.x == 0)
        out[gidx] = s / fmaxf((float)(hi - lo), 1.0f) + bldot + bl[0];
}

// =============== launcher ===============

extern "C" void kernel_launch(void* const* d_in, const int* in_sizes, int n_in,
                              void* d_out, int out_size, void* d_ws, size_t ws_size,
                              hipStream_t stream) {
    const float* x   = (const float*)d_in[0];
    const int*   ei  = (const int*)d_in[1];
    const int*   bat = (const int*)d_in[2];
    const float* W1  = (const float*)d_in[3];
    const float* b1  = (const float*)d_in[4];
    const float* W2  = (const float*)d_in[5];
    const float* b2  = (const float*)d_in[6];
    const float* W3  = (const float*)d_in[7];
    const float* b3  = (const float*)d_in[8];
    const float* Wl  = (const float*)d_in[9];
    const float* bl  = (const float*)d_in[10];

    const int N = in_sizes[0] / 128;   // 100000
    const int E = in_sizes[1] / 2;     // 1600000
    const int G = out_size;            // 1000

    const int* src = ei;
    const int* dst = ei + E;

    const int NBK = (N + BKT - 1) / BKT;       // coarse buckets (98)
    const int Np = (N + 4) & ~3;

    // workspace layout
    int*     rowptr = (int*)d_ws;                  // Np
    int*     coarse = rowptr + Np;                 // 128
    int*     bbase  = coarse + 128;                // 132 (NBK+1, padded)
    float*   w3l    = (float*)(bbase + 132);       // 64
    int*     gbcur  = (int*)(w3l + 64);            // NBK*16 padded cursors
    int*     csr    = gbcur + (size_t)NBK * 16;    // E
    int2*    pairs  = (int2*)(csr + E);            // E
    ushort4* gbA    = (ushort4*)(pairs + E);       // N*16 (bf16 features)
    ushort4* gbB    = gbA + (size_t)N * 16;        // N*16
    float*   pbuf   = (float*)(gbB + (size_t)N * 16);  // N
    float*   s_node = pbuf + N;                        // N

    // ---- CSR build + w3l ----
    hipMemsetAsync(coarse, 0, (324 + (size_t)NBK * 16) * sizeof(int), stream);
    w3l_kernel<<<1, 64, 0, stream>>>(W3, Wl, w3l);
    coarse_hist<<<256, 256, 0, stream>>>(dst, coarse, E, NBK);
    coarse_scan<<<1, 64, 0, stream>>>(coarse, bbase, NBK, E);
    partition_kernel<<<(E + EPB - 1) / EPB, 256, 0, stream>>>(src, dst, bbase, gbcur, pairs, E, NBK);
    bucket_build<<<NBK, 256, 0, stream>>>(pairs, bbase, rowptr, csr, N, E);

    const int tileGrid = (N + 15) / 16;
    const int aggGrid  = (int)(((size_t)N * 16 + 255) / 256);

    gemm1_mfma<<<(N + 63) / 64, 256, 0, stream>>>(x, W1, rowptr, (__bf16*)gbA, N);
    fused_layer_kernel<<<tileGrid, 256, 0, stream>>>(gbA, rowptr, csr, b1, W2, gbB, N);
    agg_dot2_kernel<<<aggGrid, 256, 0, stream>>>(gbB, rowptr, csr, b2, w3l, pbuf, N);
    scalar_agg<<<(N + 255) / 256, 256, 0, stream>>>(pbuf, rowptr, csr, s_node, N);
    pool_out_kernel<<<G, 64, 0, stream>>>(s_node, bat, b3, Wl, bl, (float*)d_out, N);
}